// Round 1
// baseline (4995.935 us; speedup 1.0000x reference)
//
#include <hip/hip_runtime.h>
#include <float.h>
#include <math.h>

#define LEAK 0.2f
#define EPS 1e-5f

__device__ __forceinline__ float lrelu(float v){ return v > 0.f ? v : LEAK*v; }

__device__ __forceinline__ void ln_lrelu16(float* h, const float* __restrict__ g, const float* __restrict__ be){
  float mu = 0.f;
#pragma unroll
  for (int o=0;o<16;o++) mu += h[o];
  mu *= 0.0625f;
  float var = 0.f;
#pragma unroll
  for (int o=0;o<16;o++){ float d = h[o]-mu; var += d*d; }
  var *= 0.0625f;
  float rs = 1.0f / sqrtf(var + EPS);
#pragma unroll
  for (int o=0;o<16;o++){ float v = (h[o]-mu)*rs*g[o] + be[o]; h[o] = lrelu(v); }
}

// Stage 1: per-point candidate float4 (x,y,z,|p|^2) + 3->16->16 MLP w/ LN+lrelu.
__global__ __launch_bounds__(256) void prep_kernel(const float* __restrict__ pc,
    const float* __restrict__ W0, const float* __restrict__ b0, const float* __restrict__ g0, const float* __restrict__ be0,
    const float* __restrict__ W1, const float* __restrict__ b1, const float* __restrict__ g1, const float* __restrict__ be1,
    float4* __restrict__ cand, float* __restrict__ feats)
{
  const int p = blockIdx.x*256 + threadIdx.x;      // 0 .. 256*1024-1
  const int b = p >> 10, n = p & 1023;
  const float* base = pc + b*3072;
  const float x = base[n], y = base[1024+n], z = base[2048+n];
  cand[p] = make_float4(x, y, z, x*x + y*y + z*z);
  float h[16];
#pragma unroll
  for (int o=0;o<16;o++) h[o] = b0[o] + x*W0[o] + y*W0[16+o] + z*W0[32+o];
  ln_lrelu16(h, g0, be0);
  float h2[16];
#pragma unroll
  for (int o=0;o<16;o++){
    float s = b1[o];
#pragma unroll
    for (int c=0;c<16;c++) s += h[c]*W1[c*16+o];
    h2[o] = s;
  }
  ln_lrelu16(h2, g1, be1);
  float4* fo = (float4*)(feats + p*16);
  fo[0] = make_float4(h2[0],h2[1],h2[2],h2[3]);
  fo[1] = make_float4(h2[4],h2[5],h2[6],h2[7]);
  fo[2] = make_float4(h2[8],h2[9],h2[10],h2[11]);
  fo[3] = make_float4(h2[12],h2[13],h2[14],h2[15]);
}

__device__ __forceinline__ float dist2(float4 q, float4 c){
  float dot = q.x*c.x + q.y*c.y + q.z*c.z;
  return (q.w + c.w) - 2.0f*dot;            // matches reference expansion formula
}

// KNN: one thread per query, top-16 via deferred (mask) insertion.
// QS: query stride into cand (in float4), CS: candidate stride. N: #candidates.
template<int QS, int CS>
__global__ __launch_bounds__(512) void knn_kernel(const float4* __restrict__ cand,
                                                  int* __restrict__ idx_out, int N)
{
  const int b = blockIdx.x;
  const int m = threadIdx.x;
  const int M = blockDim.x;
  const float4* __restrict__ cb = cand + b*1024;
  const float4 q = cb[m*QS];
  float dk[16]; int ik[16];
#pragma unroll
  for (int j=0;j<16;j++){ dk[j] = dist2(q, cb[j*CS]); ik[j] = j; }
  float T = dk[0]; int amax = 0;
#pragma unroll
  for (int j=1;j<16;j++){ bool g = dk[j] > T; T = g ? dk[j] : T; amax = g ? j : amax; }

  const int nch = N >> 6;
  for (int ch=0; ch<nch; ch++){
    const int cbase = ch << 6;
    unsigned long long msk = 0ull;
    if (ch == 0){
#pragma unroll
      for (int t=16;t<64;t++){
        float d2 = dist2(q, cb[t*CS]);
        if (d2 < T) msk |= (1ull << t);
      }
    } else {
#pragma unroll 16
      for (int t=0;t<64;t++){
        float d2 = dist2(q, cb[(cbase+t)*CS]);
        if (d2 < T) msk |= (1ull << t);
      }
    }
    while (msk){
      const int t = __builtin_ctzll(msk);
      msk &= msk - 1ull;
      const int n = cbase + t;
      const float d2 = dist2(q, cb[n*CS]);
      if (d2 < T){                       // T may have tightened since mask build
#pragma unroll
        for (int j=0;j<16;j++){ bool s = (j==amax); dk[j] = s ? d2 : dk[j]; ik[j] = s ? n : ik[j]; }
        T = dk[0]; amax = 0;
#pragma unroll
        for (int j=1;j<16;j++){ bool g = dk[j] > T; T = g ? dk[j] : T; amax = g ? j : amax; }
      }
    }
  }
  int4* op = (int4*)(idx_out + (b*M + m)*16);
  op[0] = make_int4(ik[0],ik[1],ik[2],ik[3]);
  op[1] = make_int4(ik[4],ik[5],ik[6],ik[7]);
  op[2] = make_int4(ik[8],ik[9],ik[10],ik[11]);
  op[3] = make_int4(ik[12],ik[13],ik[14],ik[15]);
}

// pointconv1 (19->32, maxpool over 16 NN) fused with fs = lrelu(f1 @ Ws + bs) (32->8).
__global__ __launch_bounds__(512,2) void feat1_kernel(const float4* __restrict__ cand,
    const float* __restrict__ feats, const int* __restrict__ idx1,
    const float* __restrict__ W, const float* __restrict__ Wb,
    const float* __restrict__ Ws, const float* __restrict__ bs,
    float* __restrict__ fs_out)
{
  __shared__ float sfeat[1024*16];                 // 64 KB: batch feature table
  const int b = blockIdx.x, tid = threadIdx.x;
  const float4* fb4 = (const float4*)(feats + b*16384);
  float4* sf4 = (float4*)sfeat;
#pragma unroll
  for (int i=0;i<8;i++) sf4[tid + i*512] = fb4[tid + i*512];
  __syncthreads();

  const float4* __restrict__ cb = cand + b*1024;
  const int m = tid;                               // 0..511
  const float4 q = cb[2*m];
  int idxr[16];
  { const int4* ip = (const int4*)(idx1 + (b*512+m)*16);
    int4 a=ip[0], b2=ip[1], c2=ip[2], d2=ip[3];
    idxr[0]=a.x; idxr[1]=a.y; idxr[2]=a.z; idxr[3]=a.w;
    idxr[4]=b2.x; idxr[5]=b2.y; idxr[6]=b2.z; idxr[7]=b2.w;
    idxr[8]=c2.x; idxr[9]=c2.y; idxr[10]=c2.z; idxr[11]=c2.w;
    idxr[12]=d2.x; idxr[13]=d2.y; idxr[14]=d2.z; idxr[15]=d2.w; }

  float fsacc[8] = {0.f,0.f,0.f,0.f,0.f,0.f,0.f,0.f};
  for (int og=0; og<8; og++){                      // 8 o-tiles of 4
    float wt[19][4];
#pragma unroll
    for (int c=0;c<19;c++){
      float4 t = *(const float4*)(W + c*32 + og*4);
      wt[c][0]=t.x; wt[c][1]=t.y; wt[c][2]=t.z; wt[c][3]=t.w;
    }
    float btv[4];
    { float4 t = *(const float4*)(Wb + og*4); btv[0]=t.x; btv[1]=t.y; btv[2]=t.z; btv[3]=t.w; }
    float acc[4] = {-FLT_MAX,-FLT_MAX,-FLT_MAX,-FLT_MAX};
#pragma unroll
    for (int k=0;k<16;k++){
      const int j = idxr[k];
      const float4 cj = cb[j];
      const float gx = cj.x - q.x, gy = cj.y - q.y, gz = cj.z - q.z;
      float gfv[16];
      { const float4* gf = (const float4*)(sfeat + j*16);
        float4 f0=gf[0], f1=gf[1], f2=gf[2], f3=gf[3];
        gfv[0]=f0.x; gfv[1]=f0.y; gfv[2]=f0.z; gfv[3]=f0.w;
        gfv[4]=f1.x; gfv[5]=f1.y; gfv[6]=f1.z; gfv[7]=f1.w;
        gfv[8]=f2.x; gfv[9]=f2.y; gfv[10]=f2.z; gfv[11]=f2.w;
        gfv[12]=f3.x; gfv[13]=f3.y; gfv[14]=f3.z; gfv[15]=f3.w; }
#pragma unroll
      for (int oo=0;oo<4;oo++){
        float h = btv[oo] + gx*wt[0][oo] + gy*wt[1][oo] + gz*wt[2][oo];
#pragma unroll
        for (int c=0;c<16;c++) h += gfv[c]*wt[3+c][oo];
        h = lrelu(h);
        acc[oo] = fmaxf(acc[oo], h);
      }
    }
    const float* wsrow = Ws + og*4*8;
#pragma unroll
    for (int p=0;p<8;p++)
      fsacc[p] += acc[0]*wsrow[p] + acc[1]*wsrow[8+p] + acc[2]*wsrow[16+p] + acc[3]*wsrow[24+p];
  }
  float r[8];
#pragma unroll
  for (int p=0;p<8;p++) r[p] = lrelu(fsacc[p] + bs[p]);
  float4* op = (float4*)(fs_out + (b*512+m)*8);
  op[0] = make_float4(r[0],r[1],r[2],r[3]);
  op[1] = make_float4(r[4],r[5],r[6],r[7]);
}

// pointconv2 (11->128, maxpool over 16 NN) fused with mean over queries and @We+be.
__global__ __launch_bounds__(512,2) void feat2_kernel(const float4* __restrict__ cand,
    const float* __restrict__ fs, const int* __restrict__ idx2,
    const float* __restrict__ Wc, const float* __restrict__ bc,
    const float* __restrict__ We, const float* __restrict__ beF,
    float* __restrict__ out)
{
  __shared__ float4 sxyz[512];                     // xyz1 points
  __shared__ float  sfs[512*8];                    // fs features
  __shared__ float  sred[128];                     // sum over m of f2
  const int b = blockIdx.x, tid = threadIdx.x;
  const float4* cb = cand + b*1024;
  sxyz[tid] = cb[2*tid];
  { const float4* fsb = (const float4*)(fs + b*4096);
    float4* sfs4 = (float4*)sfs;
    sfs4[tid] = fsb[tid];
    sfs4[tid+512] = fsb[tid+512]; }
  if (tid < 128) sred[tid] = 0.f;
  __syncthreads();

  const int m = tid >> 2, og4 = tid & 3;           // 128 queries x 4 o-groups
  const float4 q = sxyz[4*m];
  int idxr[16];
  { const int4* ip = (const int4*)(idx2 + (b*128+m)*16);
    int4 a=ip[0], b2=ip[1], c2=ip[2], d2=ip[3];
    idxr[0]=a.x; idxr[1]=a.y; idxr[2]=a.z; idxr[3]=a.w;
    idxr[4]=b2.x; idxr[5]=b2.y; idxr[6]=b2.z; idxr[7]=b2.w;
    idxr[8]=c2.x; idxr[9]=c2.y; idxr[10]=c2.z; idxr[11]=c2.w;
    idxr[12]=d2.x; idxr[13]=d2.y; idxr[14]=d2.z; idxr[15]=d2.w; }

  for (int og=0; og<4; og++){                      // o-tiles of 8; o0 = og4*32 + og*8
    const int o0 = og4*32 + og*8;
    float wt[11][8];
#pragma unroll
    for (int c=0;c<11;c++){
      float4 t0 = *(const float4*)(Wc + c*128 + o0);
      float4 t1 = *(const float4*)(Wc + c*128 + o0 + 4);
      wt[c][0]=t0.x; wt[c][1]=t0.y; wt[c][2]=t0.z; wt[c][3]=t0.w;
      wt[c][4]=t1.x; wt[c][5]=t1.y; wt[c][6]=t1.z; wt[c][7]=t1.w;
    }
    float btv[8];
    { float4 t0 = *(const float4*)(bc + o0); float4 t1 = *(const float4*)(bc + o0 + 4);
      btv[0]=t0.x; btv[1]=t0.y; btv[2]=t0.z; btv[3]=t0.w;
      btv[4]=t1.x; btv[5]=t1.y; btv[6]=t1.z; btv[7]=t1.w; }
    float acc[8];
#pragma unroll
    for (int oo=0;oo<8;oo++) acc[oo] = -FLT_MAX;
#pragma unroll
    for (int k=0;k<16;k++){
      const int j = idxr[k];
      const float4 cj = sxyz[j];
      const float gx = cj.x - q.x, gy = cj.y - q.y, gz = cj.z - q.z;
      float fv[8];
      { const float4* fp = (const float4*)(sfs + j*8);
        float4 f0 = fp[0], f1 = fp[1];
        fv[0]=f0.x; fv[1]=f0.y; fv[2]=f0.z; fv[3]=f0.w;
        fv[4]=f1.x; fv[5]=f1.y; fv[6]=f1.z; fv[7]=f1.w; }
#pragma unroll
      for (int oo=0;oo<8;oo++){
        float h = btv[oo] + gx*wt[0][oo] + gy*wt[1][oo] + gz*wt[2][oo];
#pragma unroll
        for (int c=0;c<8;c++) h += fv[c]*wt[3+c][oo];
        h = lrelu(h);
        acc[oo] = fmaxf(acc[oo], h);
      }
    }
#pragma unroll
    for (int oo=0;oo<8;oo++) atomicAdd(&sred[o0+oo], acc[oo]);
  }
  __syncthreads();
  if (tid < 256){
    const int o = tid;
    float s = 0.f;
#pragma unroll 8
    for (int c=0;c<128;c++) s += sred[c]*We[c*256+o];
    out[b*256+o] = beF[o] + s*0.0078125f;          // mean over 128 queries
  }
}

extern "C" void kernel_launch(void* const* d_in, const int* in_sizes, int n_in,
                              void* d_out, int out_size, void* d_ws, size_t ws_size,
                              hipStream_t stream) {
  (void)in_sizes; (void)n_in; (void)out_size; (void)ws_size;
  const float* pc   = (const float*)d_in[0];
  const float* W0   = (const float*)d_in[1];
  const float* b0   = (const float*)d_in[2];
  const float* g0   = (const float*)d_in[3];
  const float* be0  = (const float*)d_in[4];
  const float* W1   = (const float*)d_in[5];
  const float* b1   = (const float*)d_in[6];
  const float* g1   = (const float*)d_in[7];
  const float* be1  = (const float*)d_in[8];
  const float* pcW  = (const float*)d_in[9];
  const float* pcb  = (const float*)d_in[10];
  const float* Ws   = (const float*)d_in[11];
  const float* bs   = (const float*)d_in[12];
  const float* Wc   = (const float*)d_in[13];
  const float* bc   = (const float*)d_in[14];
  const float* We   = (const float*)d_in[15];
  const float* beF  = (const float*)d_in[16];

  char* ws = (char*)d_ws;
  float4* cand0 = (float4*)ws;                        // 4 MB
  float*  feats = (float*)(ws + (4u<<20));            // 16 MB
  int*    idx1  = (int*)  (ws + (20u<<20));           // 8 MB
  float*  fsb   = (float*)(ws + (28u<<20));           // 4 MB
  int*    idx2  = (int*)  (ws + (32u<<20));           // 2 MB
  float*  out   = (float*)d_out;

  prep_kernel<<<1024, 256, 0, stream>>>(pc, W0,b0,g0,be0, W1,b1,g1,be1, cand0, feats);
  knn_kernel<2,1><<<256, 512, 0, stream>>>(cand0, idx1, 1024);
  knn_kernel<8,2><<<256, 128, 0, stream>>>(cand0, idx2, 512);
  feat1_kernel<<<256, 512, 0, stream>>>(cand0, feats, idx1, pcW, pcb, Ws, bs, fsb);
  feat2_kernel<<<256, 512, 0, stream>>>(cand0, fsb, idx2, Wc, bc, We, beF, out);
}

// Round 2
// 2786.506 us; speedup vs baseline: 1.7929x; 1.7929x over previous
//
#include <hip/hip_runtime.h>
#include <float.h>
#include <math.h>

#define LEAK 0.2f
#define EPS 1e-5f

__device__ __forceinline__ float lrelu(float v){ return v > 0.f ? v : LEAK*v; }

__device__ __forceinline__ void ln_lrelu16(float* h, const float* __restrict__ g, const float* __restrict__ be){
  float mu = 0.f;
#pragma unroll
  for (int o=0;o<16;o++) mu += h[o];
  mu *= 0.0625f;
  float var = 0.f;
#pragma unroll
  for (int o=0;o<16;o++){ float d = h[o]-mu; var += d*d; }
  var *= 0.0625f;
  float rs = 1.0f / sqrtf(var + EPS);
#pragma unroll
  for (int o=0;o<16;o++){ float v = (h[o]-mu)*rs*g[o] + be[o]; h[o] = lrelu(v); }
}

// Stage 1: per-point candidate float4 (x,y,z,|p|^2) + 3->16->16 MLP w/ LN+lrelu.
__global__ __launch_bounds__(256) void prep_kernel(const float* __restrict__ pc,
    const float* __restrict__ W0, const float* __restrict__ b0, const float* __restrict__ g0, const float* __restrict__ be0,
    const float* __restrict__ W1, const float* __restrict__ b1, const float* __restrict__ g1, const float* __restrict__ be1,
    float4* __restrict__ cand, float* __restrict__ feats)
{
  const int p = blockIdx.x*256 + threadIdx.x;      // 0 .. 256*1024-1
  const int b = p >> 10, n = p & 1023;
  const float* base = pc + b*3072;
  const float x = base[n], y = base[1024+n], z = base[2048+n];
  cand[p] = make_float4(x, y, z, x*x + y*y + z*z);
  float h[16];
#pragma unroll
  for (int o=0;o<16;o++) h[o] = b0[o] + x*W0[o] + y*W0[16+o] + z*W0[32+o];
  ln_lrelu16(h, g0, be0);
  float h2[16];
#pragma unroll
  for (int o=0;o<16;o++){
    float s = b1[o];
#pragma unroll
    for (int c=0;c<16;c++) s += h[c]*W1[c*16+o];
    h2[o] = s;
  }
  ln_lrelu16(h2, g1, be1);
  float4* fo = (float4*)(feats + p*16);
  fo[0] = make_float4(h2[0],h2[1],h2[2],h2[3]);
  fo[1] = make_float4(h2[4],h2[5],h2[6],h2[7]);
  fo[2] = make_float4(h2[8],h2[9],h2[10],h2[11]);
  fo[3] = make_float4(h2[12],h2[13],h2[14],h2[15]);
}

__device__ __forceinline__ float dist2(float4 q, float4 c){
  float dot = q.x*c.x + q.y*c.y + q.z*c.z;
  return (q.w + c.w) - 2.0f*dot;            // matches reference expansion formula
}

// KNN: one thread per query, top-16 via deferred (mask) insertion.
template<int QS, int CS>
__global__ __launch_bounds__(512) void knn_kernel(const float4* __restrict__ cand,
                                                  int* __restrict__ idx_out, int N)
{
  const int b = blockIdx.x;
  const int m = threadIdx.x;
  const int M = blockDim.x;
  const float4* __restrict__ cb = cand + b*1024;
  const float4 q = cb[m*QS];
  float dk[16]; int ik[16];
#pragma unroll
  for (int j=0;j<16;j++){ dk[j] = dist2(q, cb[j*CS]); ik[j] = j; }
  float T = dk[0]; int amax = 0;
#pragma unroll
  for (int j=1;j<16;j++){ bool g = dk[j] > T; T = g ? dk[j] : T; amax = g ? j : amax; }

  const int nch = N >> 6;
  for (int ch=0; ch<nch; ch++){
    const int cbase = ch << 6;
    unsigned long long msk = 0ull;
    if (ch == 0){
#pragma unroll
      for (int t=16;t<64;t++){
        float d2 = dist2(q, cb[t*CS]);
        if (d2 < T) msk |= (1ull << t);
      }
    } else {
#pragma unroll 16
      for (int t=0;t<64;t++){
        float d2 = dist2(q, cb[(cbase+t)*CS]);
        if (d2 < T) msk |= (1ull << t);
      }
    }
    while (msk){
      const int t = __builtin_ctzll(msk);
      msk &= msk - 1ull;
      const int n = cbase + t;
      const float d2 = dist2(q, cb[n*CS]);
      if (d2 < T){
#pragma unroll
        for (int j=0;j<16;j++){ bool s = (j==amax); dk[j] = s ? d2 : dk[j]; ik[j] = s ? n : ik[j]; }
        T = dk[0]; amax = 0;
#pragma unroll
        for (int j=1;j<16;j++){ bool g = dk[j] > T; T = g ? dk[j] : T; amax = g ? j : amax; }
      }
    }
  }
  int4* op = (int4*)(idx_out + (b*M + m)*16);
  op[0] = make_int4(ik[0],ik[1],ik[2],ik[3]);
  op[1] = make_int4(ik[4],ik[5],ik[6],ik[7]);
  op[2] = make_int4(ik[8],ik[9],ik[10],ik[11]);
  op[3] = make_int4(ik[12],ik[13],ik[14],ik[15]);
}

// pointconv1 (19->32, maxpool over 16 NN) fused with fs = lrelu(f1 @ Ws + bs) (32->8).
// One block per batch (grid 256 == CU count): occupancy >1 block/CU is useless,
// so launch_bounds(512,1) -> 256-VGPR budget -> W o-tile of 8 stays in regs, NO spill.
__global__ __launch_bounds__(512,1) void feat1_kernel(const float4* __restrict__ cand,
    const float* __restrict__ feats, const int* __restrict__ idx1,
    const float* __restrict__ W, const float* __restrict__ Wb,
    const float* __restrict__ Ws, const float* __restrict__ bs,
    float* __restrict__ fs_out)
{
  __shared__ float sfeat[1024*16];                 // 64 KB: batch feature table
  const int b = blockIdx.x, tid = threadIdx.x;
  const float4* fb4 = (const float4*)(feats + b*16384);
  float4* sf4 = (float4*)sfeat;
#pragma unroll
  for (int i=0;i<8;i++) sf4[tid + i*512] = fb4[tid + i*512];
  __syncthreads();

  const float4* __restrict__ cb = cand + b*1024;
  const int m = tid;                               // 0..511
  const float4 q = cb[2*m];
  int idxr[16];
  { const int4* ip = (const int4*)(idx1 + (b*512+m)*16);
    int4 a=ip[0], b2=ip[1], c2=ip[2], d2=ip[3];
    idxr[0]=a.x; idxr[1]=a.y; idxr[2]=a.z; idxr[3]=a.w;
    idxr[4]=b2.x; idxr[5]=b2.y; idxr[6]=b2.z; idxr[7]=b2.w;
    idxr[8]=c2.x; idxr[9]=c2.y; idxr[10]=c2.z; idxr[11]=c2.w;
    idxr[12]=d2.x; idxr[13]=d2.y; idxr[14]=d2.z; idxr[15]=d2.w; }

  float fsacc[8] = {0.f,0.f,0.f,0.f,0.f,0.f,0.f,0.f};
  for (int og=0; og<4; og++){                      // 4 o-tiles of 8
    const int o0 = og*8;
    float wt[19][8];
#pragma unroll
    for (int c=0;c<19;c++){
      float4 t0 = *(const float4*)(W + c*32 + o0);
      float4 t1 = *(const float4*)(W + c*32 + o0 + 4);
      wt[c][0]=t0.x; wt[c][1]=t0.y; wt[c][2]=t0.z; wt[c][3]=t0.w;
      wt[c][4]=t1.x; wt[c][5]=t1.y; wt[c][6]=t1.z; wt[c][7]=t1.w;
    }
    float btv[8];
    { float4 t0 = *(const float4*)(Wb + o0); float4 t1 = *(const float4*)(Wb + o0 + 4);
      btv[0]=t0.x; btv[1]=t0.y; btv[2]=t0.z; btv[3]=t0.w;
      btv[4]=t1.x; btv[5]=t1.y; btv[6]=t1.z; btv[7]=t1.w; }
    float acc[8];
#pragma unroll
    for (int oo=0;oo<8;oo++) acc[oo] = -FLT_MAX;
#pragma unroll
    for (int k=0;k<16;k++){
      const int j = idxr[k];
      const float4 cj = cb[j];
      const float gx = cj.x - q.x, gy = cj.y - q.y, gz = cj.z - q.z;
      float gfv[16];
      { const float4* gf = (const float4*)(sfeat + j*16);
        float4 f0=gf[0], f1=gf[1], f2=gf[2], f3=gf[3];
        gfv[0]=f0.x; gfv[1]=f0.y; gfv[2]=f0.z; gfv[3]=f0.w;
        gfv[4]=f1.x; gfv[5]=f1.y; gfv[6]=f1.z; gfv[7]=f1.w;
        gfv[8]=f2.x; gfv[9]=f2.y; gfv[10]=f2.z; gfv[11]=f2.w;
        gfv[12]=f3.x; gfv[13]=f3.y; gfv[14]=f3.z; gfv[15]=f3.w; }
#pragma unroll
      for (int oo=0;oo<8;oo++){
        float h = btv[oo] + gx*wt[0][oo] + gy*wt[1][oo] + gz*wt[2][oo];
#pragma unroll
        for (int c=0;c<16;c++) h += gfv[c]*wt[3+c][oo];
        h = lrelu(h);
        acc[oo] = fmaxf(acc[oo], h);
      }
    }
#pragma unroll
    for (int oo=0;oo<8;oo++){
      const float* wsrow = Ws + (o0+oo)*8;
#pragma unroll
      for (int p=0;p<8;p++) fsacc[p] += acc[oo]*wsrow[p];
    }
  }
  float r[8];
#pragma unroll
  for (int p=0;p<8;p++) r[p] = lrelu(fsacc[p] + bs[p]);
  float4* op = (float4*)(fs_out + (b*512+m)*8);
  op[0] = make_float4(r[0],r[1],r[2],r[3]);
  op[1] = make_float4(r[4],r[5],r[6],r[7]);
}

// pointconv2 (11->128, maxpool over 16 NN) fused with mean over queries and @We+be.
__global__ __launch_bounds__(512,1) void feat2_kernel(const float4* __restrict__ cand,
    const float* __restrict__ fs, const int* __restrict__ idx2,
    const float* __restrict__ Wc, const float* __restrict__ bc,
    const float* __restrict__ We, const float* __restrict__ beF,
    float* __restrict__ out)
{
  __shared__ float4 sxyz[512];                     // xyz1 points
  __shared__ float  sfs[512*8];                    // fs features
  __shared__ float  sred[128];                     // sum over m of f2
  const int b = blockIdx.x, tid = threadIdx.x;
  const float4* cb = cand + b*1024;
  sxyz[tid] = cb[2*tid];
  { const float4* fsb = (const float4*)(fs + b*4096);
    float4* sfs4 = (float4*)sfs;
    sfs4[tid] = fsb[tid];
    sfs4[tid+512] = fsb[tid+512]; }
  if (tid < 128) sred[tid] = 0.f;
  __syncthreads();

  const int m = tid >> 2, og4 = tid & 3;           // 128 queries x 4 o-groups of 32
  const float4 q = sxyz[4*m];
  int idxr[16];
  { const int4* ip = (const int4*)(idx2 + (b*128+m)*16);
    int4 a=ip[0], b2=ip[1], c2=ip[2], d2=ip[3];
    idxr[0]=a.x; idxr[1]=a.y; idxr[2]=a.z; idxr[3]=a.w;
    idxr[4]=b2.x; idxr[5]=b2.y; idxr[6]=b2.z; idxr[7]=b2.w;
    idxr[8]=c2.x; idxr[9]=c2.y; idxr[10]=c2.z; idxr[11]=c2.w;
    idxr[12]=d2.x; idxr[13]=d2.y; idxr[14]=d2.z; idxr[15]=d2.w; }

  for (int og=0; og<4; og++){                      // o-tiles of 8; o0 = og4*32 + og*8
    const int o0 = og4*32 + og*8;
    float wt[11][8];
#pragma unroll
    for (int c=0;c<11;c++){
      float4 t0 = *(const float4*)(Wc + c*128 + o0);
      float4 t1 = *(const float4*)(Wc + c*128 + o0 + 4);
      wt[c][0]=t0.x; wt[c][1]=t0.y; wt[c][2]=t0.z; wt[c][3]=t0.w;
      wt[c][4]=t1.x; wt[c][5]=t1.y; wt[c][6]=t1.z; wt[c][7]=t1.w;
    }
    float btv[8];
    { float4 t0 = *(const float4*)(bc + o0); float4 t1 = *(const float4*)(bc + o0 + 4);
      btv[0]=t0.x; btv[1]=t0.y; btv[2]=t0.z; btv[3]=t0.w;
      btv[4]=t1.x; btv[5]=t1.y; btv[6]=t1.z; btv[7]=t1.w; }
    float acc[8];
#pragma unroll
    for (int oo=0;oo<8;oo++) acc[oo] = -FLT_MAX;
#pragma unroll
    for (int k=0;k<16;k++){
      const int j = idxr[k];
      const float4 cj = sxyz[j];
      const float gx = cj.x - q.x, gy = cj.y - q.y, gz = cj.z - q.z;
      float fv[8];
      { const float4* fp = (const float4*)(sfs + j*8);
        float4 f0 = fp[0], f1 = fp[1];
        fv[0]=f0.x; fv[1]=f0.y; fv[2]=f0.z; fv[3]=f0.w;
        fv[4]=f1.x; fv[5]=f1.y; fv[6]=f1.z; fv[7]=f1.w; }
#pragma unroll
      for (int oo=0;oo<8;oo++){
        float h = btv[oo] + gx*wt[0][oo] + gy*wt[1][oo] + gz*wt[2][oo];
#pragma unroll
        for (int c=0;c<8;c++) h += fv[c]*wt[3+c][oo];
        h = lrelu(h);
        acc[oo] = fmaxf(acc[oo], h);
      }
    }
    // Reduce over the 16 m-values inside this wave first (lanes sharing og4
    // differ in lane bits 2..5), then one 8-deep LDS atomic per wave.
#pragma unroll
    for (int oo=0;oo<8;oo++){
      float v = acc[oo];
      v += __shfl_xor(v, 4);
      v += __shfl_xor(v, 8);
      v += __shfl_xor(v, 16);
      v += __shfl_xor(v, 32);
      if ((threadIdx.x & 60) == 0)                 // one lane per (wave, og4)
        atomicAdd(&sred[o0+oo], v);
    }
  }
  __syncthreads();
  if (tid < 256){
    const int o = tid;
    float s = 0.f;
#pragma unroll 8
    for (int c=0;c<128;c++) s += sred[c]*We[c*256+o];
    out[b*256+o] = beF[o] + s*0.0078125f;          // mean over 128 queries
  }
}

extern "C" void kernel_launch(void* const* d_in, const int* in_sizes, int n_in,
                              void* d_out, int out_size, void* d_ws, size_t ws_size,
                              hipStream_t stream) {
  (void)in_sizes; (void)n_in; (void)out_size; (void)ws_size;
  const float* pc   = (const float*)d_in[0];
  const float* W0   = (const float*)d_in[1];
  const float* b0   = (const float*)d_in[2];
  const float* g0   = (const float*)d_in[3];
  const float* be0  = (const float*)d_in[4];
  const float* W1   = (const float*)d_in[5];
  const float* b1   = (const float*)d_in[6];
  const float* g1   = (const float*)d_in[7];
  const float* be1  = (const float*)d_in[8];
  const float* pcW  = (const float*)d_in[9];
  const float* pcb  = (const float*)d_in[10];
  const float* Ws   = (const float*)d_in[11];
  const float* bs   = (const float*)d_in[12];
  const float* Wc   = (const float*)d_in[13];
  const float* bc   = (const float*)d_in[14];
  const float* We   = (const float*)d_in[15];
  const float* beF  = (const float*)d_in[16];

  char* ws = (char*)d_ws;
  float4* cand0 = (float4*)ws;                        // 4 MB
  float*  feats = (float*)(ws + (4u<<20));            // 16 MB
  int*    idx1  = (int*)  (ws + (20u<<20));           // 8 MB
  float*  fsb   = (float*)(ws + (28u<<20));           // 4 MB
  int*    idx2  = (int*)  (ws + (32u<<20));           // 2 MB
  float*  out   = (float*)d_out;

  prep_kernel<<<1024, 256, 0, stream>>>(pc, W0,b0,g0,be0, W1,b1,g1,be1, cand0, feats);
  knn_kernel<2,1><<<256, 512, 0, stream>>>(cand0, idx1, 1024);
  knn_kernel<8,2><<<256, 128, 0, stream>>>(cand0, idx2, 512);
  feat1_kernel<<<256, 512, 0, stream>>>(cand0, feats, idx1, pcW, pcb, Ws, bs, fsb);
  feat2_kernel<<<256, 512, 0, stream>>>(cand0, fsb, idx2, Wc, bc, We, beF, out);
}

// Round 3
// 526.703 us; speedup vs baseline: 9.4853x; 5.2905x over previous
//
#include <hip/hip_runtime.h>
#include <float.h>
#include <math.h>

#define LEAK 0.2f
#define EPS 1e-5f

__device__ __forceinline__ float lrelu(float v){ return v > 0.f ? v : LEAK*v; }

__device__ __forceinline__ void ln_lrelu16(float* h, const float* __restrict__ g, const float* __restrict__ be){
  float mu = 0.f;
#pragma unroll
  for (int o=0;o<16;o++) mu += h[o];
  mu *= 0.0625f;
  float var = 0.f;
#pragma unroll
  for (int o=0;o<16;o++){ float d = h[o]-mu; var += d*d; }
  var *= 0.0625f;
  float rs = 1.0f / sqrtf(var + EPS);
#pragma unroll
  for (int o=0;o<16;o++){ float v = (h[o]-mu)*rs*g[o] + be[o]; h[o] = lrelu(v); }
}

// Stage 1: per-point candidate float4 (x,y,z,|p|^2) + 3->16->16 MLP w/ LN+lrelu.
__global__ __launch_bounds__(256) void prep_kernel(const float* __restrict__ pc,
    const float* __restrict__ W0, const float* __restrict__ b0, const float* __restrict__ g0, const float* __restrict__ be0,
    const float* __restrict__ W1, const float* __restrict__ b1, const float* __restrict__ g1, const float* __restrict__ be1,
    float4* __restrict__ cand, float* __restrict__ feats)
{
  const int p = blockIdx.x*256 + threadIdx.x;      // 0 .. 256*1024-1
  const int b = p >> 10, n = p & 1023;
  const float* base = pc + b*3072;
  const float x = base[n], y = base[1024+n], z = base[2048+n];
  cand[p] = make_float4(x, y, z, x*x + y*y + z*z);
  float h[16];
#pragma unroll
  for (int o=0;o<16;o++) h[o] = b0[o] + x*W0[o] + y*W0[16+o] + z*W0[32+o];
  ln_lrelu16(h, g0, be0);
  float h2[16];
#pragma unroll
  for (int o=0;o<16;o++){
    float s = b1[o];
#pragma unroll
    for (int c=0;c<16;c++) s += h[c]*W1[c*16+o];
    h2[o] = s;
  }
  ln_lrelu16(h2, g1, be1);
  float4* fo = (float4*)(feats + p*16);
  fo[0] = make_float4(h2[0],h2[1],h2[2],h2[3]);
  fo[1] = make_float4(h2[4],h2[5],h2[6],h2[7]);
  fo[2] = make_float4(h2[8],h2[9],h2[10],h2[11]);
  fo[3] = make_float4(h2[12],h2[13],h2[14],h2[15]);
}

__device__ __forceinline__ float dist2(float4 q, float4 c){
  float dot = q.x*c.x + q.y*c.y + q.z*c.z;
  return (q.w + c.w) - 2.0f*dot;            // matches reference expansion formula
}

// KNN: one thread per query, top-16 via deferred (mask) insertion.
template<int QS, int CS>
__global__ __launch_bounds__(512) void knn_kernel(const float4* __restrict__ cand,
                                                  int* __restrict__ idx_out, int N)
{
  const int b = blockIdx.x;
  const int m = threadIdx.x;
  const int M = blockDim.x;
  const float4* __restrict__ cb = cand + b*1024;
  const float4 q = cb[m*QS];
  float dk[16]; int ik[16];
#pragma unroll
  for (int j=0;j<16;j++){ dk[j] = dist2(q, cb[j*CS]); ik[j] = j; }
  float T = dk[0]; int amax = 0;
#pragma unroll
  for (int j=1;j<16;j++){ bool g = dk[j] > T; T = g ? dk[j] : T; amax = g ? j : amax; }

  const int nch = N >> 6;
  for (int ch=0; ch<nch; ch++){
    const int cbase = ch << 6;
    unsigned long long msk = 0ull;
    if (ch == 0){
#pragma unroll
      for (int t=16;t<64;t++){
        float d2 = dist2(q, cb[t*CS]);
        if (d2 < T) msk |= (1ull << t);
      }
    } else {
#pragma unroll 16
      for (int t=0;t<64;t++){
        float d2 = dist2(q, cb[(cbase+t)*CS]);
        if (d2 < T) msk |= (1ull << t);
      }
    }
    while (msk){
      const int t = __builtin_ctzll(msk);
      msk &= msk - 1ull;
      const int n = cbase + t;
      const float d2 = dist2(q, cb[n*CS]);
      if (d2 < T){
#pragma unroll
        for (int j=0;j<16;j++){ bool s = (j==amax); dk[j] = s ? d2 : dk[j]; ik[j] = s ? n : ik[j]; }
        T = dk[0]; amax = 0;
#pragma unroll
        for (int j=1;j<16;j++){ bool g = dk[j] > T; T = g ? dk[j] : T; amax = g ? j : amax; }
      }
    }
  }
  int4* op = (int4*)(idx_out + (b*M + m)*16);
  op[0] = make_int4(ik[0],ik[1],ik[2],ik[3]);
  op[1] = make_int4(ik[4],ik[5],ik[6],ik[7]);
  op[2] = make_int4(ik[8],ik[9],ik[10],ik[11]);
  op[3] = make_int4(ik[12],ik[13],ik[14],ik[15]);
}

// pointconv1 (19->32, maxpool over 16 NN) fused with fs = lrelu(f1 @ Ws + bs) (32->8).
// grid 256 == CU count, one block/CU. waves_per_eu(2,2): 8-wave block = 2 waves/SIMD
// -> VGPR budget 512/2 = 256, so the 19x8 W-tile (152 regs) stays resident, NO spill.
// (launch_bounds alone left the LDS-derived 4-waves/EU bound -> 128-reg cap -> 5 GB
//  of scratch traffic = the whole round-2 runtime.)
__global__ __attribute__((amdgpu_flat_work_group_size(512,512), amdgpu_waves_per_eu(2,2)))
void feat1_kernel(const float4* __restrict__ cand,
    const float* __restrict__ feats, const int* __restrict__ idx1,
    const float* __restrict__ W, const float* __restrict__ Wb,
    const float* __restrict__ Ws, const float* __restrict__ bs,
    float* __restrict__ fs_out)
{
  __shared__ float sfeat[1024*16];                 // 64 KB: batch feature table
  const int b = blockIdx.x, tid = threadIdx.x;
  const float4* fb4 = (const float4*)(feats + b*16384);
  float4* sf4 = (float4*)sfeat;
#pragma unroll
  for (int i=0;i<8;i++) sf4[tid + i*512] = fb4[tid + i*512];
  __syncthreads();

  const float4* __restrict__ cb = cand + b*1024;
  const int m = tid;                               // 0..511
  const float4 q = cb[2*m];
  int idxr[16];
  { const int4* ip = (const int4*)(idx1 + (b*512+m)*16);
    int4 a=ip[0], b2=ip[1], c2=ip[2], d2=ip[3];
    idxr[0]=a.x; idxr[1]=a.y; idxr[2]=a.z; idxr[3]=a.w;
    idxr[4]=b2.x; idxr[5]=b2.y; idxr[6]=b2.z; idxr[7]=b2.w;
    idxr[8]=c2.x; idxr[9]=c2.y; idxr[10]=c2.z; idxr[11]=c2.w;
    idxr[12]=d2.x; idxr[13]=d2.y; idxr[14]=d2.z; idxr[15]=d2.w; }

  float fsacc[8] = {0.f,0.f,0.f,0.f,0.f,0.f,0.f,0.f};
  for (int og=0; og<4; og++){                      // 4 o-tiles of 8
    const int o0 = og*8;
    float wt[19][8];
#pragma unroll
    for (int c=0;c<19;c++){
      float4 t0 = *(const float4*)(W + c*32 + o0);
      float4 t1 = *(const float4*)(W + c*32 + o0 + 4);
      wt[c][0]=t0.x; wt[c][1]=t0.y; wt[c][2]=t0.z; wt[c][3]=t0.w;
      wt[c][4]=t1.x; wt[c][5]=t1.y; wt[c][6]=t1.z; wt[c][7]=t1.w;
    }
    float btv[8];
    { float4 t0 = *(const float4*)(Wb + o0); float4 t1 = *(const float4*)(Wb + o0 + 4);
      btv[0]=t0.x; btv[1]=t0.y; btv[2]=t0.z; btv[3]=t0.w;
      btv[4]=t1.x; btv[5]=t1.y; btv[6]=t1.z; btv[7]=t1.w; }
    float acc[8];
#pragma unroll
    for (int oo=0;oo<8;oo++) acc[oo] = -FLT_MAX;
#pragma unroll
    for (int k=0;k<16;k++){
      const int j = idxr[k];
      const float4 cj = cb[j];
      const float gx = cj.x - q.x, gy = cj.y - q.y, gz = cj.z - q.z;
      float h[8];
#pragma unroll
      for (int oo=0;oo<8;oo++)
        h[oo] = btv[oo] + gx*wt[0][oo] + gy*wt[1][oo] + gz*wt[2][oo];
      const float4* gf = (const float4*)(sfeat + j*16);
#pragma unroll
      for (int cc=0;cc<4;cc++){                    // chunked gather: max-live stays low
        float4 f = gf[cc];
#pragma unroll
        for (int oo=0;oo<8;oo++)
          h[oo] += f.x*wt[3+4*cc][oo] + f.y*wt[4+4*cc][oo] + f.z*wt[5+4*cc][oo] + f.w*wt[6+4*cc][oo];
      }
#pragma unroll
      for (int oo=0;oo<8;oo++) acc[oo] = fmaxf(acc[oo], lrelu(h[oo]));
    }
#pragma unroll
    for (int oo=0;oo<8;oo++){
      const float* wsrow = Ws + (o0+oo)*8;
#pragma unroll
      for (int p=0;p<8;p++) fsacc[p] += acc[oo]*wsrow[p];
    }
  }
  float r[8];
#pragma unroll
  for (int p=0;p<8;p++) r[p] = lrelu(fsacc[p] + bs[p]);
  float4* op = (float4*)(fs_out + (b*512+m)*8);
  op[0] = make_float4(r[0],r[1],r[2],r[3]);
  op[1] = make_float4(r[4],r[5],r[6],r[7]);
}

// pointconv2 (11->128, maxpool over 16 NN) fused with mean over queries and @We+be.
__global__ __attribute__((amdgpu_flat_work_group_size(512,512), amdgpu_waves_per_eu(2,2)))
void feat2_kernel(const float4* __restrict__ cand,
    const float* __restrict__ fs, const int* __restrict__ idx2,
    const float* __restrict__ Wc, const float* __restrict__ bc,
    const float* __restrict__ We, const float* __restrict__ beF,
    float* __restrict__ out)
{
  __shared__ float4 sxyz[512];                     // xyz1 points
  __shared__ float  sfs[512*8];                    // fs features
  __shared__ float  sred[128];                     // sum over m of f2
  const int b = blockIdx.x, tid = threadIdx.x;
  const float4* cb = cand + b*1024;
  sxyz[tid] = cb[2*tid];
  { const float4* fsb = (const float4*)(fs + b*4096);
    float4* sfs4 = (float4*)sfs;
    sfs4[tid] = fsb[tid];
    sfs4[tid+512] = fsb[tid+512]; }
  if (tid < 128) sred[tid] = 0.f;
  __syncthreads();

  const int m = tid >> 2, og4 = tid & 3;           // 128 queries x 4 o-groups of 32
  const float4 q = sxyz[4*m];
  int idxr[16];
  { const int4* ip = (const int4*)(idx2 + (b*128+m)*16);
    int4 a=ip[0], b2=ip[1], c2=ip[2], d2=ip[3];
    idxr[0]=a.x; idxr[1]=a.y; idxr[2]=a.z; idxr[3]=a.w;
    idxr[4]=b2.x; idxr[5]=b2.y; idxr[6]=b2.z; idxr[7]=b2.w;
    idxr[8]=c2.x; idxr[9]=c2.y; idxr[10]=c2.z; idxr[11]=c2.w;
    idxr[12]=d2.x; idxr[13]=d2.y; idxr[14]=d2.z; idxr[15]=d2.w; }

  for (int og=0; og<4; og++){                      // o-tiles of 8; o0 = og4*32 + og*8
    const int o0 = og4*32 + og*8;
    float wt[11][8];
#pragma unroll
    for (int c=0;c<11;c++){
      float4 t0 = *(const float4*)(Wc + c*128 + o0);
      float4 t1 = *(const float4*)(Wc + c*128 + o0 + 4);
      wt[c][0]=t0.x; wt[c][1]=t0.y; wt[c][2]=t0.z; wt[c][3]=t0.w;
      wt[c][4]=t1.x; wt[c][5]=t1.y; wt[c][6]=t1.z; wt[c][7]=t1.w;
    }
    float btv[8];
    { float4 t0 = *(const float4*)(bc + o0); float4 t1 = *(const float4*)(bc + o0 + 4);
      btv[0]=t0.x; btv[1]=t0.y; btv[2]=t0.z; btv[3]=t0.w;
      btv[4]=t1.x; btv[5]=t1.y; btv[6]=t1.z; btv[7]=t1.w; }
    float acc[8];
#pragma unroll
    for (int oo=0;oo<8;oo++) acc[oo] = -FLT_MAX;
#pragma unroll
    for (int k=0;k<16;k++){
      const int j = idxr[k];
      const float4 cj = sxyz[j];
      const float gx = cj.x - q.x, gy = cj.y - q.y, gz = cj.z - q.z;
      float h[8];
#pragma unroll
      for (int oo=0;oo<8;oo++)
        h[oo] = btv[oo] + gx*wt[0][oo] + gy*wt[1][oo] + gz*wt[2][oo];
      const float4* fp = (const float4*)(sfs + j*8);
#pragma unroll
      for (int cc=0;cc<2;cc++){
        float4 f = fp[cc];
#pragma unroll
        for (int oo=0;oo<8;oo++)
          h[oo] += f.x*wt[3+4*cc][oo] + f.y*wt[4+4*cc][oo] + f.z*wt[5+4*cc][oo] + f.w*wt[6+4*cc][oo];
      }
#pragma unroll
      for (int oo=0;oo<8;oo++) acc[oo] = fmaxf(acc[oo], lrelu(h[oo]));
    }
    // Reduce over the 16 m-values inside this wave first (lanes sharing og4
    // differ in lane bits 2..5), then one 8-deep LDS atomic per wave.
#pragma unroll
    for (int oo=0;oo<8;oo++){
      float v = acc[oo];
      v += __shfl_xor(v, 4);
      v += __shfl_xor(v, 8);
      v += __shfl_xor(v, 16);
      v += __shfl_xor(v, 32);
      if ((threadIdx.x & 60) == 0)                 // one lane per (wave, og4)
        atomicAdd(&sred[o0+oo], v);
    }
  }
  __syncthreads();
  if (tid < 256){
    const int o = tid;
    float s = 0.f;
#pragma unroll 8
    for (int c=0;c<128;c++) s += sred[c]*We[c*256+o];
    out[b*256+o] = beF[o] + s*0.0078125f;          // mean over 128 queries
  }
}

extern "C" void kernel_launch(void* const* d_in, const int* in_sizes, int n_in,
                              void* d_out, int out_size, void* d_ws, size_t ws_size,
                              hipStream_t stream) {
  (void)in_sizes; (void)n_in; (void)out_size; (void)ws_size;
  const float* pc   = (const float*)d_in[0];
  const float* W0   = (const float*)d_in[1];
  const float* b0   = (const float*)d_in[2];
  const float* g0   = (const float*)d_in[3];
  const float* be0  = (const float*)d_in[4];
  const float* W1   = (const float*)d_in[5];
  const float* b1   = (const float*)d_in[6];
  const float* g1   = (const float*)d_in[7];
  const float* be1  = (const float*)d_in[8];
  const float* pcW  = (const float*)d_in[9];
  const float* pcb  = (const float*)d_in[10];
  const float* Ws   = (const float*)d_in[11];
  const float* bs   = (const float*)d_in[12];
  const float* Wc   = (const float*)d_in[13];
  const float* bc   = (const float*)d_in[14];
  const float* We   = (const float*)d_in[15];
  const float* beF  = (const float*)d_in[16];

  char* ws = (char*)d_ws;
  float4* cand0 = (float4*)ws;                        // 4 MB
  float*  feats = (float*)(ws + (4u<<20));            // 16 MB
  int*    idx1  = (int*)  (ws + (20u<<20));           // 8 MB
  float*  fsb   = (float*)(ws + (28u<<20));           // 4 MB
  int*    idx2  = (int*)  (ws + (32u<<20));           // 2 MB
  float*  out   = (float*)d_out;

  prep_kernel<<<1024, 256, 0, stream>>>(pc, W0,b0,g0,be0, W1,b1,g1,be1, cand0, feats);
  knn_kernel<2,1><<<256, 512, 0, stream>>>(cand0, idx1, 1024);
  knn_kernel<8,2><<<256, 128, 0, stream>>>(cand0, idx2, 512);
  feat1_kernel<<<256, 512, 0, stream>>>(cand0, feats, idx1, pcW, pcb, Ws, bs, fsb);
  feat2_kernel<<<256, 512, 0, stream>>>(cand0, fsb, idx2, Wc, bc, We, beF, out);
}

// Round 4
// 518.476 us; speedup vs baseline: 9.6358x; 1.0159x over previous
//
#include <hip/hip_runtime.h>
#include <float.h>
#include <math.h>

#define LEAK 0.2f
#define EPS 1e-5f

__device__ __forceinline__ float lrelu(float v){ return v > 0.f ? v : LEAK*v; }

__device__ __forceinline__ void ln_lrelu16(float* h, const float* __restrict__ g, const float* __restrict__ be){
  float mu = 0.f;
#pragma unroll
  for (int o=0;o<16;o++) mu += h[o];
  mu *= 0.0625f;
  float var = 0.f;
#pragma unroll
  for (int o=0;o<16;o++){ float d = h[o]-mu; var += d*d; }
  var *= 0.0625f;
  float rs = 1.0f / sqrtf(var + EPS);
#pragma unroll
  for (int o=0;o<16;o++){ float v = (h[o]-mu)*rs*g[o] + be[o]; h[o] = lrelu(v); }
}

// Stage 1: per-point candidate float4 (x,y,z,|p|^2) + 3->16->16 MLP w/ LN+lrelu.
__global__ __launch_bounds__(256) void prep_kernel(const float* __restrict__ pc,
    const float* __restrict__ W0, const float* __restrict__ b0, const float* __restrict__ g0, const float* __restrict__ be0,
    const float* __restrict__ W1, const float* __restrict__ b1, const float* __restrict__ g1, const float* __restrict__ be1,
    float4* __restrict__ cand, float* __restrict__ feats)
{
  const int p = blockIdx.x*256 + threadIdx.x;      // 0 .. 256*1024-1
  const int b = p >> 10, n = p & 1023;
  const float* base = pc + b*3072;
  const float x = base[n], y = base[1024+n], z = base[2048+n];
  cand[p] = make_float4(x, y, z, x*x + y*y + z*z);
  float h[16];
#pragma unroll
  for (int o=0;o<16;o++) h[o] = b0[o] + x*W0[o] + y*W0[16+o] + z*W0[32+o];
  ln_lrelu16(h, g0, be0);
  float h2[16];
#pragma unroll
  for (int o=0;o<16;o++){
    float s = b1[o];
#pragma unroll
    for (int c=0;c<16;c++) s += h[c]*W1[c*16+o];
    h2[o] = s;
  }
  ln_lrelu16(h2, g1, be1);
  float4* fo = (float4*)(feats + p*16);
  fo[0] = make_float4(h2[0],h2[1],h2[2],h2[3]);
  fo[1] = make_float4(h2[4],h2[5],h2[6],h2[7]);
  fo[2] = make_float4(h2[8],h2[9],h2[10],h2[11]);
  fo[3] = make_float4(h2[12],h2[13],h2[14],h2[15]);
}

__device__ __forceinline__ void topk_insert(float (&dk)[16], int (&ik)[16],
                                            float &T, int &amax, float d, int n){
#pragma unroll
  for (int j=0;j<16;j++){ bool s=(j==amax); dk[j]=s?d:dk[j]; ik[j]=s?n:ik[j]; }
  T = dk[0]; amax = 0;
#pragma unroll
  for (int j=1;j<16;j++){ bool g=dk[j]>T; T=g?dk[j]:T; amax=g?j:amax; }
}

// KNN top-16, SPLIT threads per query (each scans NCAND/SPLIT candidates),
// LDS merge of partial lists. Distances kept in d' = |c|^2 - 2 q.c space
// (q.w folded out: order-preserving, 3 FMA per candidate).
// QS: query stride (float4), CS: candidate stride, NQ: #queries, NCAND: #candidates.
template<int QS, int CS, int NQ, int SPLIT, int NCAND>
__global__ __attribute__((amdgpu_flat_work_group_size(NQ*SPLIT, NQ*SPLIT)))
void knn_kernel(const float4* __restrict__ cand, int* __restrict__ idx_out)
{
  constexpr int NC = NCAND / SPLIT;                // candidates per thread
  __shared__ float md[(SPLIT-1)*NQ*16];
  __shared__ int   mi[(SPLIT-1)*NQ*16];
  const int b = blockIdx.x;
  const int tid = threadIdx.x;
  const int m = tid & (NQ-1);
  const int s = tid / NQ;
  const float4* __restrict__ cb = cand + b*1024;
  const float4 qv = cb[m*QS];
  const float qx2 = -2.f*qv.x, qy2 = -2.f*qv.y, qz2 = -2.f*qv.z;
  const int n0 = s*NC;

  float dk[16]; int ik[16];
#pragma unroll
  for (int j=0;j<16;j++){ dk[j] = FLT_MAX; ik[j] = 0; }
  float T = FLT_MAX; int amax = 0;

  // chunk 0: threshold is loose, nearly every candidate inserts -> direct
  // insertion from the scan register (no mask, no recompute loads).
#pragma unroll 8
  for (int t=0;t<64;t++){
    float4 c = cb[(n0+t)*CS];
    float d = fmaf(c.x,qx2, fmaf(c.y,qy2, fmaf(c.z,qz2, c.w)));
    if (d < T) topk_insert(dk,ik,T,amax,d,n0+t);
  }
  // later chunks: deferred-mask (while-loop count = per-lane flagged count,
  // not any-lane-per-candidate).
  for (int ch=1; ch<NC/64; ch++){
    const int cb0 = n0 + ch*64;
    unsigned long long msk = 0ull;
#pragma unroll 16
    for (int t=0;t<64;t++){
      float4 c = cb[(cb0+t)*CS];
      float d = fmaf(c.x,qx2, fmaf(c.y,qy2, fmaf(c.z,qz2, c.w)));
      if (d < T) msk |= (1ull<<t);
    }
    while (msk){
      const int t = __builtin_ctzll(msk);
      msk &= msk-1ull;
      float4 c = cb[(cb0+t)*CS];
      float d = fmaf(c.x,qx2, fmaf(c.y,qy2, fmaf(c.z,qz2, c.w)));
      if (d < T) topk_insert(dk,ik,T,amax,d,cb0+t);
    }
  }

  if (s > 0){
    const int base = ((s-1)*NQ + m)*16;
#pragma unroll
    for (int j=0;j<16;j++){ md[base+j] = dk[j]; mi[base+j] = ik[j]; }
  }
  __syncthreads();
  if (s == 0){
#pragma unroll
    for (int sp=0; sp<SPLIT-1; sp++){
      const int base = (sp*NQ + m)*16;
#pragma unroll
      for (int j=0;j<16;j++){
        float d = md[base+j]; int n = mi[base+j];
        if (d < T) topk_insert(dk,ik,T,amax,d,n);
      }
    }
    int4* op = (int4*)(idx_out + (b*NQ + m)*16);
    op[0] = make_int4(ik[0],ik[1],ik[2],ik[3]);
    op[1] = make_int4(ik[4],ik[5],ik[6],ik[7]);
    op[2] = make_int4(ik[8],ik[9],ik[10],ik[11]);
    op[3] = make_int4(ik[12],ik[13],ik[14],ik[15]);
  }
}

// pointconv1 (19->32, maxpool over 16 NN) fused with fs = lrelu(f1 @ Ws + bs) (32->8).
// grid 256 == CU count, one block/CU. waves_per_eu(2,2): 8-wave block = 2 waves/SIMD
// -> VGPR budget 512/2 = 256, so the 19x8 W-tile (152 regs) stays resident, NO spill.
__global__ __attribute__((amdgpu_flat_work_group_size(512,512), amdgpu_waves_per_eu(2,2)))
void feat1_kernel(const float4* __restrict__ cand,
    const float* __restrict__ feats, const int* __restrict__ idx1,
    const float* __restrict__ W, const float* __restrict__ Wb,
    const float* __restrict__ Ws, const float* __restrict__ bs,
    float* __restrict__ fs_out)
{
  __shared__ float sfeat[1024*16];                 // 64 KB: batch feature table
  const int b = blockIdx.x, tid = threadIdx.x;
  const float4* fb4 = (const float4*)(feats + b*16384);
  float4* sf4 = (float4*)sfeat;
#pragma unroll
  for (int i=0;i<8;i++) sf4[tid + i*512] = fb4[tid + i*512];
  __syncthreads();

  const float4* __restrict__ cb = cand + b*1024;
  const int m = tid;                               // 0..511
  const float4 q = cb[2*m];
  int idxr[16];
  { const int4* ip = (const int4*)(idx1 + (b*512+m)*16);
    int4 a=ip[0], b2=ip[1], c2=ip[2], d2=ip[3];
    idxr[0]=a.x; idxr[1]=a.y; idxr[2]=a.z; idxr[3]=a.w;
    idxr[4]=b2.x; idxr[5]=b2.y; idxr[6]=b2.z; idxr[7]=b2.w;
    idxr[8]=c2.x; idxr[9]=c2.y; idxr[10]=c2.z; idxr[11]=c2.w;
    idxr[12]=d2.x; idxr[13]=d2.y; idxr[14]=d2.z; idxr[15]=d2.w; }

  float fsacc[8] = {0.f,0.f,0.f,0.f,0.f,0.f,0.f,0.f};
  for (int og=0; og<4; og++){                      // 4 o-tiles of 8
    const int o0 = og*8;
    float wt[19][8];
#pragma unroll
    for (int c=0;c<19;c++){
      float4 t0 = *(const float4*)(W + c*32 + o0);
      float4 t1 = *(const float4*)(W + c*32 + o0 + 4);
      wt[c][0]=t0.x; wt[c][1]=t0.y; wt[c][2]=t0.z; wt[c][3]=t0.w;
      wt[c][4]=t1.x; wt[c][5]=t1.y; wt[c][6]=t1.z; wt[c][7]=t1.w;
    }
    float btv[8];
    { float4 t0 = *(const float4*)(Wb + o0); float4 t1 = *(const float4*)(Wb + o0 + 4);
      btv[0]=t0.x; btv[1]=t0.y; btv[2]=t0.z; btv[3]=t0.w;
      btv[4]=t1.x; btv[5]=t1.y; btv[6]=t1.z; btv[7]=t1.w; }
    float acc[8];
#pragma unroll
    for (int oo=0;oo<8;oo++) acc[oo] = -FLT_MAX;
#pragma unroll
    for (int k=0;k<16;k++){
      const int j = idxr[k];
      const float4 cj = cb[j];
      const float gx = cj.x - q.x, gy = cj.y - q.y, gz = cj.z - q.z;
      float h[8];
#pragma unroll
      for (int oo=0;oo<8;oo++)
        h[oo] = btv[oo] + gx*wt[0][oo] + gy*wt[1][oo] + gz*wt[2][oo];
      const float4* gf = (const float4*)(sfeat + j*16);
#pragma unroll
      for (int cc=0;cc<4;cc++){                    // chunked gather: max-live stays low
        float4 f = gf[cc];
#pragma unroll
        for (int oo=0;oo<8;oo++)
          h[oo] += f.x*wt[3+4*cc][oo] + f.y*wt[4+4*cc][oo] + f.z*wt[5+4*cc][oo] + f.w*wt[6+4*cc][oo];
      }
#pragma unroll
      for (int oo=0;oo<8;oo++) acc[oo] = fmaxf(acc[oo], lrelu(h[oo]));
    }
#pragma unroll
    for (int oo=0;oo<8;oo++){
      const float* wsrow = Ws + (o0+oo)*8;
#pragma unroll
      for (int p=0;p<8;p++) fsacc[p] += acc[oo]*wsrow[p];
    }
  }
  float r[8];
#pragma unroll
  for (int p=0;p<8;p++) r[p] = lrelu(fsacc[p] + bs[p]);
  float4* op = (float4*)(fs_out + (b*512+m)*8);
  op[0] = make_float4(r[0],r[1],r[2],r[3]);
  op[1] = make_float4(r[4],r[5],r[6],r[7]);
}

// pointconv2 (11->128, maxpool over 16 NN) fused with mean over queries and @We+be.
__global__ __attribute__((amdgpu_flat_work_group_size(512,512), amdgpu_waves_per_eu(2,2)))
void feat2_kernel(const float4* __restrict__ cand,
    const float* __restrict__ fs, const int* __restrict__ idx2,
    const float* __restrict__ Wc, const float* __restrict__ bc,
    const float* __restrict__ We, const float* __restrict__ beF,
    float* __restrict__ out)
{
  __shared__ float4 sxyz[512];                     // xyz1 points
  __shared__ float  sfs[512*8];                    // fs features
  __shared__ float  sred[128];                     // sum over m of f2
  const int b = blockIdx.x, tid = threadIdx.x;
  const float4* cb = cand + b*1024;
  sxyz[tid] = cb[2*tid];
  { const float4* fsb = (const float4*)(fs + b*4096);
    float4* sfs4 = (float4*)sfs;
    sfs4[tid] = fsb[tid];
    sfs4[tid+512] = fsb[tid+512]; }
  if (tid < 128) sred[tid] = 0.f;
  __syncthreads();

  const int m = tid >> 2, og4 = tid & 3;           // 128 queries x 4 o-groups of 32
  const float4 q = sxyz[4*m];
  int idxr[16];
  { const int4* ip = (const int4*)(idx2 + (b*128+m)*16);
    int4 a=ip[0], b2=ip[1], c2=ip[2], d2=ip[3];
    idxr[0]=a.x; idxr[1]=a.y; idxr[2]=a.z; idxr[3]=a.w;
    idxr[4]=b2.x; idxr[5]=b2.y; idxr[6]=b2.z; idxr[7]=b2.w;
    idxr[8]=c2.x; idxr[9]=c2.y; idxr[10]=c2.z; idxr[11]=c2.w;
    idxr[12]=d2.x; idxr[13]=d2.y; idxr[14]=d2.z; idxr[15]=d2.w; }

  for (int og=0; og<4; og++){                      // o-tiles of 8; o0 = og4*32 + og*8
    const int o0 = og4*32 + og*8;
    float wt[11][8];
#pragma unroll
    for (int c=0;c<11;c++){
      float4 t0 = *(const float4*)(Wc + c*128 + o0);
      float4 t1 = *(const float4*)(Wc + c*128 + o0 + 4);
      wt[c][0]=t0.x; wt[c][1]=t0.y; wt[c][2]=t0.z; wt[c][3]=t0.w;
      wt[c][4]=t1.x; wt[c][5]=t1.y; wt[c][6]=t1.z; wt[c][7]=t1.w;
    }
    float btv[8];
    { float4 t0 = *(const float4*)(bc + o0); float4 t1 = *(const float4*)(bc + o0 + 4);
      btv[0]=t0.x; btv[1]=t0.y; btv[2]=t0.z; btv[3]=t0.w;
      btv[4]=t1.x; btv[5]=t1.y; btv[6]=t1.z; btv[7]=t1.w; }
    float acc[8];
#pragma unroll
    for (int oo=0;oo<8;oo++) acc[oo] = -FLT_MAX;
#pragma unroll
    for (int k=0;k<16;k++){
      const int j = idxr[k];
      const float4 cj = sxyz[j];
      const float gx = cj.x - q.x, gy = cj.y - q.y, gz = cj.z - q.z;
      float h[8];
#pragma unroll
      for (int oo=0;oo<8;oo++)
        h[oo] = btv[oo] + gx*wt[0][oo] + gy*wt[1][oo] + gz*wt[2][oo];
      const float4* fp = (const float4*)(sfs + j*8);
#pragma unroll
      for (int cc=0;cc<2;cc++){
        float4 f = fp[cc];
#pragma unroll
        for (int oo=0;oo<8;oo++)
          h[oo] += f.x*wt[3+4*cc][oo] + f.y*wt[4+4*cc][oo] + f.z*wt[5+4*cc][oo] + f.w*wt[6+4*cc][oo];
      }
#pragma unroll
      for (int oo=0;oo<8;oo++) acc[oo] = fmaxf(acc[oo], lrelu(h[oo]));
    }
    // Reduce over the 16 m-values inside this wave first (lanes sharing og4
    // differ in lane bits 2..5), then one 8-deep LDS atomic per wave.
#pragma unroll
    for (int oo=0;oo<8;oo++){
      float v = acc[oo];
      v += __shfl_xor(v, 4);
      v += __shfl_xor(v, 8);
      v += __shfl_xor(v, 16);
      v += __shfl_xor(v, 32);
      if ((threadIdx.x & 60) == 0)                 // one lane per (wave, og4)
        atomicAdd(&sred[o0+oo], v);
    }
  }
  __syncthreads();
  if (tid < 256){
    const int o = tid;
    float s = 0.f;
#pragma unroll 8
    for (int c=0;c<128;c++) s += sred[c]*We[c*256+o];
    out[b*256+o] = beF[o] + s*0.0078125f;          // mean over 128 queries
  }
}

extern "C" void kernel_launch(void* const* d_in, const int* in_sizes, int n_in,
                              void* d_out, int out_size, void* d_ws, size_t ws_size,
                              hipStream_t stream) {
  (void)in_sizes; (void)n_in; (void)out_size; (void)ws_size;
  const float* pc   = (const float*)d_in[0];
  const float* W0   = (const float*)d_in[1];
  const float* b0   = (const float*)d_in[2];
  const float* g0   = (const float*)d_in[3];
  const float* be0  = (const float*)d_in[4];
  const float* W1   = (const float*)d_in[5];
  const float* b1   = (const float*)d_in[6];
  const float* g1   = (const float*)d_in[7];
  const float* be1  = (const float*)d_in[8];
  const float* pcW  = (const float*)d_in[9];
  const float* pcb  = (const float*)d_in[10];
  const float* Ws   = (const float*)d_in[11];
  const float* bs   = (const float*)d_in[12];
  const float* Wc   = (const float*)d_in[13];
  const float* bc   = (const float*)d_in[14];
  const float* We   = (const float*)d_in[15];
  const float* beF  = (const float*)d_in[16];

  char* ws = (char*)d_ws;
  float4* cand0 = (float4*)ws;                        // 4 MB
  float*  feats = (float*)(ws + (4u<<20));            // 16 MB
  int*    idx1  = (int*)  (ws + (20u<<20));           // 8 MB
  float*  fsb   = (float*)(ws + (28u<<20));           // 4 MB
  int*    idx2  = (int*)  (ws + (32u<<20));           // 2 MB
  float*  out   = (float*)d_out;

  prep_kernel<<<1024, 256, 0, stream>>>(pc, W0,b0,g0,be0, W1,b1,g1,be1, cand0, feats);
  knn_kernel<2,1,512,2,1024><<<256, 1024, 0, stream>>>(cand0, idx1);
  knn_kernel<8,2,128,4, 512><<<256,  512, 0, stream>>>(cand0, idx2);
  feat1_kernel<<<256, 512, 0, stream>>>(cand0, feats, idx1, pcW, pcb, Ws, bs, fsb);
  feat2_kernel<<<256, 512, 0, stream>>>(cand0, fsb, idx2, Wc, bc, We, beF, out);
}

// Round 6
// 486.779 us; speedup vs baseline: 10.2632x; 1.0651x over previous
//
#include <hip/hip_runtime.h>
#include <float.h>
#include <math.h>

#define LEAK 0.2f
#define EPS 1e-5f

__device__ __forceinline__ float lrelu(float v){ return v > 0.f ? v : LEAK*v; }

__device__ __forceinline__ void ln_lrelu16(float* h, const float* __restrict__ g, const float* __restrict__ be){
  float mu = 0.f;
#pragma unroll
  for (int o=0;o<16;o++) mu += h[o];
  mu *= 0.0625f;
  float var = 0.f;
#pragma unroll
  for (int o=0;o<16;o++){ float d = h[o]-mu; var += d*d; }
  var *= 0.0625f;
  float rs = 1.0f / sqrtf(var + EPS);
#pragma unroll
  for (int o=0;o<16;o++){ float v = (h[o]-mu)*rs*g[o] + be[o]; h[o] = lrelu(v); }
}

// Stage 1: per-point candidate float4 (x,y,z,|p|^2) + 3->16->16 MLP w/ LN+lrelu.
__global__ __launch_bounds__(256) void prep_kernel(const float* __restrict__ pc,
    const float* __restrict__ W0, const float* __restrict__ b0, const float* __restrict__ g0, const float* __restrict__ be0,
    const float* __restrict__ W1, const float* __restrict__ b1, const float* __restrict__ g1, const float* __restrict__ be1,
    float4* __restrict__ cand, float* __restrict__ feats)
{
  const int p = blockIdx.x*256 + threadIdx.x;      // 0 .. 256*1024-1
  const int b = p >> 10, n = p & 1023;
  const float* base = pc + b*3072;
  const float x = base[n], y = base[1024+n], z = base[2048+n];
  cand[p] = make_float4(x, y, z, x*x + y*y + z*z);
  float h[16];
#pragma unroll
  for (int o=0;o<16;o++) h[o] = b0[o] + x*W0[o] + y*W0[16+o] + z*W0[32+o];
  ln_lrelu16(h, g0, be0);
  float h2[16];
#pragma unroll
  for (int o=0;o<16;o++){
    float s = b1[o];
#pragma unroll
    for (int c=0;c<16;c++) s += h[c]*W1[c*16+o];
    h2[o] = s;
  }
  ln_lrelu16(h2, g1, be1);
  float4* fo = (float4*)(feats + p*16);
  fo[0] = make_float4(h2[0],h2[1],h2[2],h2[3]);
  fo[1] = make_float4(h2[4],h2[5],h2[6],h2[7]);
  fo[2] = make_float4(h2[8],h2[9],h2[10],h2[11]);
  fo[3] = make_float4(h2[12],h2[13],h2[14],h2[15]);
}

// ---- packed top-k keys: ordered-uint(distance) with 10 index bits in the LSBs.
// NOTE: sentinel must NOT be 0xFFFFFFFF — that decodes to NaN (all-ones exponent),
// and `d < NaN` is false, which silently kills all insertions (round-5 bug).
// Real keys always decode finite: truncation+index bits only touch low mantissa.
#define KNN_SENT 0xFF7FFC00u   // enc_key(FLT_MAX, 0): finite, larger than any real key
__device__ __forceinline__ unsigned enc_key(float d, int n){
  unsigned u = __float_as_uint(d);
  u ^= (unsigned)(((int)u) >> 31) | 0x80000000u;   // total-order transform
  return (u & ~1023u) | (unsigned)n;
}
__device__ __forceinline__ float dec_key(unsigned k){
  unsigned u = k ^ ((unsigned)(~(((int)k) >> 31)) | 0x80000000u);
  return __uint_as_float(u);
}

__device__ __forceinline__ void topk_ins(unsigned (&dk)[16], unsigned &Tu, float &Tf,
                                         int &amax, unsigned key){
#pragma unroll
  for (int j=0;j<16;j++) dk[j] = (j==amax) ? key : dk[j];
  Tu = dk[0]; amax = 0;
#pragma unroll
  for (int j=1;j<16;j++){ bool g = dk[j] > Tu; Tu = g?dk[j]:Tu; amax = g?j:amax; }
  Tf = dec_key(Tu);
}

// KNN top-16, SPLIT threads per query, one u32 key array (16 VGPRs), LDS merge
// (transposed layout md[j][col] -> lane-major -> conflict-free).
template<int QS, int CS, int NQ, int SPLIT, int NCAND>
__global__ __attribute__((amdgpu_flat_work_group_size(NQ*SPLIT, NQ*SPLIT), amdgpu_waves_per_eu(4,4)))
void knn_kernel(const float4* __restrict__ cand, int* __restrict__ idx_out)
{
  constexpr int NC = NCAND / SPLIT;                // candidates per thread
  constexpr int MW = (SPLIT-1)*NQ;
  __shared__ unsigned md[16*MW];
  const int b = blockIdx.x, tid = threadIdx.x;
  const int m = tid & (NQ-1), s = tid / NQ;
  const float4* __restrict__ cb = cand + b*1024;
  const float4 qv = cb[m*QS];
  const float qx2=-2.f*qv.x, qy2=-2.f*qv.y, qz2=-2.f*qv.z;
  const int n0 = s*NC;

  unsigned dk[16];
#pragma unroll
  for (int j=0;j<16;j++) dk[j] = KNN_SENT;
  unsigned Tu = KNN_SENT; int amax = 0; float Tf = dec_key(KNN_SENT);

  // chunk 0: loose threshold -> direct insertion (no mask/recompute).
#pragma unroll 8
  for (int t=0;t<64;t++){
    float4 c = cb[(n0+t)*CS];
    float d = fmaf(c.x,qx2, fmaf(c.y,qy2, fmaf(c.z,qz2, c.w)));
    if (d < Tf) topk_ins(dk,Tu,Tf,amax, enc_key(d, n0+t));
  }
  // later chunks: deferred-mask; scan is 3 FMA + cmp in float space.
  for (int ch=1; ch<NC/64; ch++){
    const int cb0 = n0 + ch*64;
    unsigned long long msk = 0ull;
#pragma unroll 16
    for (int t=0;t<64;t++){
      float4 c = cb[(cb0+t)*CS];
      float d = fmaf(c.x,qx2, fmaf(c.y,qy2, fmaf(c.z,qz2, c.w)));
      if (d < Tf) msk |= (1ull<<t);
    }
    while (msk){
      const int t = __builtin_ctzll(msk);
      msk &= msk-1ull;
      float4 c = cb[(cb0+t)*CS];
      float d = fmaf(c.x,qx2, fmaf(c.y,qy2, fmaf(c.z,qz2, c.w)));
      if (d < Tf) topk_ins(dk,Tu,Tf,amax, enc_key(d, cb0+t));
    }
  }

  if (s > 0){
    const int col = (s-1)*NQ + m;
#pragma unroll
    for (int j=0;j<16;j++) md[j*MW + col] = dk[j];
  }
  __syncthreads();
  if (s == 0){
#pragma unroll
    for (int sp=0; sp<SPLIT-1; sp++){
      const int col = sp*NQ + m;
#pragma unroll
      for (int j=0;j<16;j++){
        unsigned key = md[j*MW + col];
        if (key < Tu) topk_ins(dk,Tu,Tf,amax,key);
      }
    }
    int ik[16];
#pragma unroll
    for (int j=0;j<16;j++) ik[j] = (int)(dk[j] & 1023u);
    int4* op = (int4*)(idx_out + (b*NQ + m)*16);
    op[0] = make_int4(ik[0],ik[1],ik[2],ik[3]);
    op[1] = make_int4(ik[4],ik[5],ik[6],ik[7]);
    op[2] = make_int4(ik[8],ik[9],ik[10],ik[11]);
    op[3] = make_int4(ik[12],ik[13],ik[14],ik[15]);
  }
}

// pointconv1 (19->32, maxpool over 16 NN) fused with fs = lrelu(f1 @ Ws + bs).
// o-tile of 4: wt[19][4]=76 regs -> total live ~125, fits the 128-VGPR cap with
// no spill. sfeat stride 20 floats (16B-aligned, bank-quad start spreads over 8
// positions) kills the j-parity 16-way b128 conflicts; xyz as b32 arrays.
__global__ __attribute__((amdgpu_flat_work_group_size(512,512), amdgpu_waves_per_eu(2,2)))
void feat1_kernel(const float4* __restrict__ cand,
    const float* __restrict__ feats, const int* __restrict__ idx1,
    const float* __restrict__ W, const float* __restrict__ Wb,
    const float* __restrict__ Ws, const float* __restrict__ bs,
    float* __restrict__ fs_out)
{
  __shared__ float sfeat[1024*20];                 // 80 KB, stride 20
  __shared__ float sx[1024], sy[1024], sz[1024];   // 12 KB
  const int b = blockIdx.x, tid = threadIdx.x;
  const float4* fb4 = (const float4*)(feats + b*16384);
  float4* sf4 = (float4*)sfeat;
#pragma unroll
  for (int i=0;i<8;i++){
    int idx = tid + i*512;                         // float4 id 0..4095
    float4 v = fb4[idx];
    sf4[(idx>>2)*5 + (idx&3)] = v;
  }
  const float4* __restrict__ cb = cand + b*1024;
  { float4 c0 = cb[tid], c1 = cb[tid+512];
    sx[tid]=c0.x; sy[tid]=c0.y; sz[tid]=c0.z;
    sx[tid+512]=c1.x; sy[tid+512]=c1.y; sz[tid+512]=c1.z; }
  __syncthreads();

  const int m = tid;                               // 0..511
  const float qx = sx[2*m], qy = sy[2*m], qz = sz[2*m];
  int idxr[16];
  { const int4* ip = (const int4*)(idx1 + (b*512+m)*16);
    int4 a=ip[0], b2=ip[1], c2=ip[2], d2=ip[3];
    idxr[0]=a.x; idxr[1]=a.y; idxr[2]=a.z; idxr[3]=a.w;
    idxr[4]=b2.x; idxr[5]=b2.y; idxr[6]=b2.z; idxr[7]=b2.w;
    idxr[8]=c2.x; idxr[9]=c2.y; idxr[10]=c2.z; idxr[11]=c2.w;
    idxr[12]=d2.x; idxr[13]=d2.y; idxr[14]=d2.z; idxr[15]=d2.w; }

  float fsacc[8] = {0.f,0.f,0.f,0.f,0.f,0.f,0.f,0.f};
  for (int og=0; og<8; og++){                      // 8 o-tiles of 4
    const int o0 = og*4;
    float wt[19][4];
#pragma unroll
    for (int c=0;c<19;c++){
      float4 t = *(const float4*)(W + c*32 + o0);
      wt[c][0]=t.x; wt[c][1]=t.y; wt[c][2]=t.z; wt[c][3]=t.w;
    }
    float btv[4];
    { float4 t = *(const float4*)(Wb + o0);
      btv[0]=t.x; btv[1]=t.y; btv[2]=t.z; btv[3]=t.w; }
    float acc[4] = {-FLT_MAX,-FLT_MAX,-FLT_MAX,-FLT_MAX};
#pragma unroll
    for (int k=0;k<16;k++){
      const int j = idxr[k];
      const float gx = sx[j]-qx, gy = sy[j]-qy, gz = sz[j]-qz;
      float h[4];
#pragma unroll
      for (int oo=0;oo<4;oo++)
        h[oo] = btv[oo] + gx*wt[0][oo] + gy*wt[1][oo] + gz*wt[2][oo];
      const float4* gf = (const float4*)(sfeat + j*20);
#pragma unroll
      for (int cc=0;cc<4;cc++){
        float4 f = gf[cc];
#pragma unroll
        for (int oo=0;oo<4;oo++)
          h[oo] += f.x*wt[3+4*cc][oo] + f.y*wt[4+4*cc][oo] + f.z*wt[5+4*cc][oo] + f.w*wt[6+4*cc][oo];
      }
#pragma unroll
      for (int oo=0;oo<4;oo++) acc[oo] = fmaxf(acc[oo], lrelu(h[oo]));
    }
#pragma unroll
    for (int oo=0;oo<4;oo++){
      const float* wsrow = Ws + (o0+oo)*8;
#pragma unroll
      for (int p=0;p<8;p++) fsacc[p] += acc[oo]*wsrow[p];
    }
  }
  float r[8];
#pragma unroll
  for (int p=0;p<8;p++) r[p] = lrelu(fsacc[p] + bs[p]);
  float4* op = (float4*)(fs_out + (b*512+m)*8);
  op[0] = make_float4(r[0],r[1],r[2],r[3]);
  op[1] = make_float4(r[4],r[5],r[6],r[7]);
}

// pointconv2 (11->128, maxpool over 16 NN) fused with mean over queries and @We+be.
// o-tile of 4 (wt[11][4]=44 regs); sfs stride 12; xyz as b32 arrays.
__global__ __attribute__((amdgpu_flat_work_group_size(512,512), amdgpu_waves_per_eu(2,2)))
void feat2_kernel(const float4* __restrict__ cand,
    const float* __restrict__ fs, const int* __restrict__ idx2,
    const float* __restrict__ Wc, const float* __restrict__ bc,
    const float* __restrict__ We, const float* __restrict__ beF,
    float* __restrict__ out)
{
  __shared__ float sfs[512*12];                    // 24 KB, stride 12
  __shared__ float sx[512], sy[512], sz[512];      // 6 KB
  __shared__ float sred[128];
  const int b = blockIdx.x, tid = threadIdx.x;
  const float4* cb = cand + b*1024;
  { float4 c0 = cb[2*tid];
    sx[tid]=c0.x; sy[tid]=c0.y; sz[tid]=c0.z; }
  { const float4* fsb = (const float4*)(fs + b*4096);
    float4* sfs4 = (float4*)sfs;
#pragma unroll
    for (int i=0;i<2;i++){
      int idx = tid + i*512;                       // float4 id 0..1023
      float4 v = fsb[idx];
      sfs4[(idx>>1)*3 + (idx&1)] = v;
    } }
  if (tid < 128) sred[tid] = 0.f;
  __syncthreads();

  const int m = tid >> 2, og4 = tid & 3;           // 128 queries x 4 o-groups of 32
  const float qx = sx[4*m], qy = sy[4*m], qz = sz[4*m];
  int idxr[16];
  { const int4* ip = (const int4*)(idx2 + (b*128+m)*16);
    int4 a=ip[0], b2=ip[1], c2=ip[2], d2=ip[3];
    idxr[0]=a.x; idxr[1]=a.y; idxr[2]=a.z; idxr[3]=a.w;
    idxr[4]=b2.x; idxr[5]=b2.y; idxr[6]=b2.z; idxr[7]=b2.w;
    idxr[8]=c2.x; idxr[9]=c2.y; idxr[10]=c2.z; idxr[11]=c2.w;
    idxr[12]=d2.x; idxr[13]=d2.y; idxr[14]=d2.z; idxr[15]=d2.w; }

  for (int og=0; og<8; og++){                      // 8 o-tiles of 4; o0 = og4*32 + og*4
    const int o0 = og4*32 + og*4;
    float wt[11][4];
#pragma unroll
    for (int c=0;c<11;c++){
      float4 t = *(const float4*)(Wc + c*128 + o0);
      wt[c][0]=t.x; wt[c][1]=t.y; wt[c][2]=t.z; wt[c][3]=t.w;
    }
    float btv[4];
    { float4 t = *(const float4*)(bc + o0);
      btv[0]=t.x; btv[1]=t.y; btv[2]=t.z; btv[3]=t.w; }
    float acc[4] = {-FLT_MAX,-FLT_MAX,-FLT_MAX,-FLT_MAX};
#pragma unroll
    for (int k=0;k<16;k++){
      const int j = idxr[k];
      const float gx = sx[j]-qx, gy = sy[j]-qy, gz = sz[j]-qz;
      float h[4];
#pragma unroll
      for (int oo=0;oo<4;oo++)
        h[oo] = btv[oo] + gx*wt[0][oo] + gy*wt[1][oo] + gz*wt[2][oo];
      const float4* fp = (const float4*)(sfs + j*12);
#pragma unroll
      for (int cc=0;cc<2;cc++){
        float4 f = fp[cc];
#pragma unroll
        for (int oo=0;oo<4;oo++)
          h[oo] += f.x*wt[3+4*cc][oo] + f.y*wt[4+4*cc][oo] + f.z*wt[5+4*cc][oo] + f.w*wt[6+4*cc][oo];
      }
#pragma unroll
      for (int oo=0;oo<4;oo++) acc[oo] = fmaxf(acc[oo], lrelu(h[oo]));
    }
    // reduce over the 16 m-values in this wave (lane bits 2..5), then one atomic.
#pragma unroll
    for (int oo=0;oo<4;oo++){
      float v = acc[oo];
      v += __shfl_xor(v, 4);
      v += __shfl_xor(v, 8);
      v += __shfl_xor(v, 16);
      v += __shfl_xor(v, 32);
      if ((threadIdx.x & 60) == 0)                 // one lane per (wave, og4)
        atomicAdd(&sred[o0+oo], v);
    }
  }
  __syncthreads();
  if (tid < 256){
    const int o = tid;
    float s = 0.f;
#pragma unroll 8
    for (int c=0;c<128;c++) s += sred[c]*We[c*256+o];
    out[b*256+o] = beF[o] + s*0.0078125f;          // mean over 128 queries
  }
}

extern "C" void kernel_launch(void* const* d_in, const int* in_sizes, int n_in,
                              void* d_out, int out_size, void* d_ws, size_t ws_size,
                              hipStream_t stream) {
  (void)in_sizes; (void)n_in; (void)out_size; (void)ws_size;
  const float* pc   = (const float*)d_in[0];
  const float* W0   = (const float*)d_in[1];
  const float* b0   = (const float*)d_in[2];
  const float* g0   = (const float*)d_in[3];
  const float* be0  = (const float*)d_in[4];
  const float* W1   = (const float*)d_in[5];
  const float* b1   = (const float*)d_in[6];
  const float* g1   = (const float*)d_in[7];
  const float* be1  = (const float*)d_in[8];
  const float* pcW  = (const float*)d_in[9];
  const float* pcb  = (const float*)d_in[10];
  const float* Ws   = (const float*)d_in[11];
  const float* bs   = (const float*)d_in[12];
  const float* Wc   = (const float*)d_in[13];
  const float* bc   = (const float*)d_in[14];
  const float* We   = (const float*)d_in[15];
  const float* beF  = (const float*)d_in[16];

  char* ws = (char*)d_ws;
  float4* cand0 = (float4*)ws;                        // 4 MB
  float*  feats = (float*)(ws + (4u<<20));            // 16 MB
  int*    idx1  = (int*)  (ws + (20u<<20));           // 8 MB
  float*  fsb   = (float*)(ws + (28u<<20));           // 4 MB
  int*    idx2  = (int*)  (ws + (32u<<20));           // 2 MB
  float*  out   = (float*)d_out;

  prep_kernel<<<1024, 256, 0, stream>>>(pc, W0,b0,g0,be0, W1,b1,g1,be1, cand0, feats);
  knn_kernel<2,1,512,2,1024><<<256, 1024, 0, stream>>>(cand0, idx1);
  knn_kernel<8,2,128,4, 512><<<256,  512, 0, stream>>>(cand0, idx2);
  feat1_kernel<<<256, 512, 0, stream>>>(cand0, feats, idx1, pcW, pcb, Ws, bs, fsb);
  feat2_kernel<<<256, 512, 0, stream>>>(cand0, fsb, idx2, Wc, bc, We, beF, out);
}

// Round 7
// 420.107 us; speedup vs baseline: 11.8920x; 1.1587x over previous
//
#include <hip/hip_runtime.h>
#include <float.h>
#include <math.h>

#define LEAK 0.2f
#define EPS 1e-5f

__device__ __forceinline__ float lrelu(float v){ return v > 0.f ? v : LEAK*v; }

__device__ __forceinline__ void ln_lrelu16(float* h, const float* __restrict__ g, const float* __restrict__ be){
  float mu = 0.f;
#pragma unroll
  for (int o=0;o<16;o++) mu += h[o];
  mu *= 0.0625f;
  float var = 0.f;
#pragma unroll
  for (int o=0;o<16;o++){ float d = h[o]-mu; var += d*d; }
  var *= 0.0625f;
  float rs = 1.0f / sqrtf(var + EPS);
#pragma unroll
  for (int o=0;o<16;o++){ float v = (h[o]-mu)*rs*g[o] + be[o]; h[o] = lrelu(v); }
}

// Stage 1: per-point candidate float4 (x,y,z,|p|^2) + 3->16->16 MLP w/ LN+lrelu.
__global__ __launch_bounds__(256) void prep_kernel(const float* __restrict__ pc,
    const float* __restrict__ W0, const float* __restrict__ b0, const float* __restrict__ g0, const float* __restrict__ be0,
    const float* __restrict__ W1, const float* __restrict__ b1, const float* __restrict__ g1, const float* __restrict__ be1,
    float4* __restrict__ cand, float* __restrict__ feats)
{
  const int p = blockIdx.x*256 + threadIdx.x;      // 0 .. 256*1024-1
  const int b = p >> 10, n = p & 1023;
  const float* base = pc + b*3072;
  const float x = base[n], y = base[1024+n], z = base[2048+n];
  cand[p] = make_float4(x, y, z, x*x + y*y + z*z);
  float h[16];
#pragma unroll
  for (int o=0;o<16;o++) h[o] = b0[o] + x*W0[o] + y*W0[16+o] + z*W0[32+o];
  ln_lrelu16(h, g0, be0);
  float h2[16];
#pragma unroll
  for (int o=0;o<16;o++){
    float s = b1[o];
#pragma unroll
    for (int c=0;c<16;c++) s += h[c]*W1[c*16+o];
    h2[o] = s;
  }
  ln_lrelu16(h2, g1, be1);
  float4* fo = (float4*)(feats + p*16);
  fo[0] = make_float4(h2[0],h2[1],h2[2],h2[3]);
  fo[1] = make_float4(h2[4],h2[5],h2[6],h2[7]);
  fo[2] = make_float4(h2[8],h2[9],h2[10],h2[11]);
  fo[3] = make_float4(h2[12],h2[13],h2[14],h2[15]);
}

// ---- packed top-k keys: ordered-uint(distance) with 10 index bits in the LSBs.
// Sentinel must NOT be 0xFFFFFFFF (decodes to NaN -> kills all compares).
#define KNN_SENT 0xFF7FFC00u   // enc_key(FLT_MAX, 0): finite, larger than any real key
__device__ __forceinline__ unsigned enc_key(float d, int n){
  unsigned u = __float_as_uint(d);
  u ^= (unsigned)(((int)u) >> 31) | 0x80000000u;   // total-order transform
  return (u & ~1023u) | (unsigned)n;
}
__device__ __forceinline__ float dec_key(unsigned k){
  unsigned u = k ^ ((unsigned)(~(((int)k) >> 31)) | 0x80000000u);
  return __uint_as_float(u);
}

// Branchless insert into ASCENDING sorted dk[16]; drops the current max.
// new[j] = min( max(old[j-1], key), old[j] ) — 2 VALU per slot, no rescans,
// no exec-mask divergence; key >= dk[15] is a mathematical no-op (self-reject).
__device__ __forceinline__ void ins_sorted(unsigned (&dk)[16], unsigned key){
  unsigned prev = key;                 // = max(old dk[j-1], key), with dk[-1]:=key
#pragma unroll
  for (int j=0;j<16;j++){
    unsigned cur = dk[j];
    dk[j] = prev < cur ? prev : cur;
    prev  = cur > key ? cur : key;
  }
}

// KNN top-16, SPLIT threads per query, sorted u32-key list in 16 VGPRs.
// Fill-16 unconditional, then masked scan (deferred trips, unconditional insert).
template<int QS, int CS, int NQ, int SPLIT, int NCAND>
__global__ __attribute__((amdgpu_flat_work_group_size(NQ*SPLIT, NQ*SPLIT), amdgpu_waves_per_eu(4,4)))
void knn_kernel(const float4* __restrict__ cand, int* __restrict__ idx_out)
{
  constexpr int NC = NCAND / SPLIT;                // candidates per thread
  constexpr int MW = (SPLIT-1)*NQ;
  __shared__ unsigned md[16*MW];
  const int b = blockIdx.x, tid = threadIdx.x;
  const int m = tid & (NQ-1), s = tid / NQ;
  const float4* __restrict__ cb = cand + b*1024;
  const float4 qv = cb[m*QS];
  const float qx2=-2.f*qv.x, qy2=-2.f*qv.y, qz2=-2.f*qv.z;
  const int n0 = s*NC;

  unsigned dk[16];
#pragma unroll
  for (int j=0;j<16;j++) dk[j] = KNN_SENT;

  // fill: first 16 candidates of this thread's range, unconditional.
#pragma unroll
  for (int t=0;t<16;t++){
    float4 c = cb[(n0+t)*CS];
    float d = fmaf(c.x,qx2, fmaf(c.y,qy2, fmaf(c.z,qz2, c.w)));
    ins_sorted(dk, enc_key(d, n0+t));
  }
  float Tf = dec_key(dk[15]);

  // masked scan: flag pass (3 FMA + cmp), then wave-max trips with
  // branchless unconditional insert (stale flags self-reject).
  for (int ch=0; ch<NC/64; ch++){
    const int cb0 = n0 + ch*64;
    unsigned long long msk = 0ull;
    if (ch == 0){
#pragma unroll
      for (int t=16;t<64;t++){
        float4 c = cb[(cb0+t)*CS];
        float d = fmaf(c.x,qx2, fmaf(c.y,qy2, fmaf(c.z,qz2, c.w)));
        if (d < Tf) msk |= (1ull<<t);
      }
    } else {
#pragma unroll 16
      for (int t=0;t<64;t++){
        float4 c = cb[(cb0+t)*CS];
        float d = fmaf(c.x,qx2, fmaf(c.y,qy2, fmaf(c.z,qz2, c.w)));
        if (d < Tf) msk |= (1ull<<t);
      }
    }
    while (msk){
      const int t = __builtin_ctzll(msk);
      msk &= msk-1ull;
      float4 c = cb[(cb0+t)*CS];
      float d = fmaf(c.x,qx2, fmaf(c.y,qy2, fmaf(c.z,qz2, c.w)));
      ins_sorted(dk, enc_key(d, cb0+t));
    }
    Tf = dec_key(dk[15]);
  }

  if (s > 0){
    const int col = (s-1)*NQ + m;
#pragma unroll
    for (int j=0;j<16;j++) md[j*MW + col] = dk[j];
  }
  __syncthreads();
  if (s == 0){
    if (SPLIT == 2){
      // both lists sorted ascending: 16 smallest of the union is the
      // elementwise min with the other list reversed (bitonic lower half).
      // Result is unsorted — fine, neighbor order is irrelevant (maxpool).
      const int col = m;
#pragma unroll
      for (int j=0;j<16;j++){
        unsigned o = md[(15-j)*MW + col];
        dk[j] = o < dk[j] ? o : dk[j];
      }
    } else {
#pragma unroll
      for (int sp=0; sp<SPLIT-1; sp++){
        const int col = sp*NQ + m;
#pragma unroll
        for (int j=0;j<16;j++) ins_sorted(dk, md[j*MW + col]);
      }
    }
    int ik[16];
#pragma unroll
    for (int j=0;j<16;j++) ik[j] = (int)(dk[j] & 1023u);
    int4* op = (int4*)(idx_out + (b*NQ + m)*16);
    op[0] = make_int4(ik[0],ik[1],ik[2],ik[3]);
    op[1] = make_int4(ik[4],ik[5],ik[6],ik[7]);
    op[2] = make_int4(ik[8],ik[9],ik[10],ik[11]);
    op[3] = make_int4(ik[12],ik[13],ik[14],ik[15]);
  }
}

// pointconv1 (19->32, maxpool over 16 NN) fused with fs = lrelu(f1 @ Ws + bs).
// o-tile of 4: fits the 128-VGPR cap with no spill. sfeat stride 20 floats;
// xyz as b32 arrays (random-j b32 ~2 lanes/bank = free).
__global__ __attribute__((amdgpu_flat_work_group_size(512,512), amdgpu_waves_per_eu(2,2)))
void feat1_kernel(const float4* __restrict__ cand,
    const float* __restrict__ feats, const int* __restrict__ idx1,
    const float* __restrict__ W, const float* __restrict__ Wb,
    const float* __restrict__ Ws, const float* __restrict__ bs,
    float* __restrict__ fs_out)
{
  __shared__ float sfeat[1024*20];                 // 80 KB, stride 20
  __shared__ float sx[1024], sy[1024], sz[1024];   // 12 KB
  const int b = blockIdx.x, tid = threadIdx.x;
  const float4* fb4 = (const float4*)(feats + b*16384);
  float4* sf4 = (float4*)sfeat;
#pragma unroll
  for (int i=0;i<8;i++){
    int idx = tid + i*512;                         // float4 id 0..4095
    float4 v = fb4[idx];
    sf4[(idx>>2)*5 + (idx&3)] = v;
  }
  const float4* __restrict__ cb = cand + b*1024;
  { float4 c0 = cb[tid], c1 = cb[tid+512];
    sx[tid]=c0.x; sy[tid]=c0.y; sz[tid]=c0.z;
    sx[tid+512]=c1.x; sy[tid+512]=c1.y; sz[tid+512]=c1.z; }
  __syncthreads();

  const int m = tid;                               // 0..511
  const float qx = sx[2*m], qy = sy[2*m], qz = sz[2*m];
  int idxr[16];
  { const int4* ip = (const int4*)(idx1 + (b*512+m)*16);
    int4 a=ip[0], b2=ip[1], c2=ip[2], d2=ip[3];
    idxr[0]=a.x; idxr[1]=a.y; idxr[2]=a.z; idxr[3]=a.w;
    idxr[4]=b2.x; idxr[5]=b2.y; idxr[6]=b2.z; idxr[7]=b2.w;
    idxr[8]=c2.x; idxr[9]=c2.y; idxr[10]=c2.z; idxr[11]=c2.w;
    idxr[12]=d2.x; idxr[13]=d2.y; idxr[14]=d2.z; idxr[15]=d2.w; }

  float fsacc[8] = {0.f,0.f,0.f,0.f,0.f,0.f,0.f,0.f};
  for (int og=0; og<8; og++){                      // 8 o-tiles of 4
    const int o0 = og*4;
    float wt[19][4];
#pragma unroll
    for (int c=0;c<19;c++){
      float4 t = *(const float4*)(W + c*32 + o0);
      wt[c][0]=t.x; wt[c][1]=t.y; wt[c][2]=t.z; wt[c][3]=t.w;
    }
    float btv[4];
    { float4 t = *(const float4*)(Wb + o0);
      btv[0]=t.x; btv[1]=t.y; btv[2]=t.z; btv[3]=t.w; }
    float acc[4] = {-FLT_MAX,-FLT_MAX,-FLT_MAX,-FLT_MAX};
#pragma unroll
    for (int k=0;k<16;k++){
      const int j = idxr[k];
      const float gx = sx[j]-qx, gy = sy[j]-qy, gz = sz[j]-qz;
      float h[4];
#pragma unroll
      for (int oo=0;oo<4;oo++)
        h[oo] = btv[oo] + gx*wt[0][oo] + gy*wt[1][oo] + gz*wt[2][oo];
      const float4* gf = (const float4*)(sfeat + j*20);
#pragma unroll
      for (int cc=0;cc<4;cc++){
        float4 f = gf[cc];
#pragma unroll
        for (int oo=0;oo<4;oo++)
          h[oo] += f.x*wt[3+4*cc][oo] + f.y*wt[4+4*cc][oo] + f.z*wt[5+4*cc][oo] + f.w*wt[6+4*cc][oo];
      }
#pragma unroll
      for (int oo=0;oo<4;oo++) acc[oo] = fmaxf(acc[oo], lrelu(h[oo]));
    }
#pragma unroll
    for (int oo=0;oo<4;oo++){
      const float* wsrow = Ws + (o0+oo)*8;
#pragma unroll
      for (int p=0;p<8;p++) fsacc[p] += acc[oo]*wsrow[p];
    }
  }
  float r[8];
#pragma unroll
  for (int p=0;p<8;p++) r[p] = lrelu(fsacc[p] + bs[p]);
  float4* op = (float4*)(fs_out + (b*512+m)*8);
  op[0] = make_float4(r[0],r[1],r[2],r[3]);
  op[1] = make_float4(r[4],r[5],r[6],r[7]);
}

// pointconv2 (11->128, maxpool over 16 NN) fused with mean over queries and @We+be.
__global__ __attribute__((amdgpu_flat_work_group_size(512,512), amdgpu_waves_per_eu(2,2)))
void feat2_kernel(const float4* __restrict__ cand,
    const float* __restrict__ fs, const int* __restrict__ idx2,
    const float* __restrict__ Wc, const float* __restrict__ bc,
    const float* __restrict__ We, const float* __restrict__ beF,
    float* __restrict__ out)
{
  __shared__ float sfs[512*12];                    // 24 KB, stride 12
  __shared__ float sx[512], sy[512], sz[512];      // 6 KB
  __shared__ float sred[128];
  const int b = blockIdx.x, tid = threadIdx.x;
  const float4* cb = cand + b*1024;
  { float4 c0 = cb[2*tid];
    sx[tid]=c0.x; sy[tid]=c0.y; sz[tid]=c0.z; }
  { const float4* fsb = (const float4*)(fs + b*4096);
    float4* sfs4 = (float4*)sfs;
#pragma unroll
    for (int i=0;i<2;i++){
      int idx = tid + i*512;                       // float4 id 0..1023
      float4 v = fsb[idx];
      sfs4[(idx>>1)*3 + (idx&1)] = v;
    } }
  if (tid < 128) sred[tid] = 0.f;
  __syncthreads();

  const int m = tid >> 2, og4 = tid & 3;           // 128 queries x 4 o-groups of 32
  const float qx = sx[4*m], qy = sy[4*m], qz = sz[4*m];
  int idxr[16];
  { const int4* ip = (const int4*)(idx2 + (b*128+m)*16);
    int4 a=ip[0], b2=ip[1], c2=ip[2], d2=ip[3];
    idxr[0]=a.x; idxr[1]=a.y; idxr[2]=a.z; idxr[3]=a.w;
    idxr[4]=b2.x; idxr[5]=b2.y; idxr[6]=b2.z; idxr[7]=b2.w;
    idxr[8]=c2.x; idxr[9]=c2.y; idxr[10]=c2.z; idxr[11]=c2.w;
    idxr[12]=d2.x; idxr[13]=d2.y; idxr[14]=d2.z; idxr[15]=d2.w; }

  for (int og=0; og<8; og++){                      // 8 o-tiles of 4; o0 = og4*32 + og*4
    const int o0 = og4*32 + og*4;
    float wt[11][4];
#pragma unroll
    for (int c=0;c<11;c++){
      float4 t = *(const float4*)(Wc + c*128 + o0);
      wt[c][0]=t.x; wt[c][1]=t.y; wt[c][2]=t.z; wt[c][3]=t.w;
    }
    float btv[4];
    { float4 t = *(const float4*)(bc + o0);
      btv[0]=t.x; btv[1]=t.y; btv[2]=t.z; btv[3]=t.w; }
    float acc[4] = {-FLT_MAX,-FLT_MAX,-FLT_MAX,-FLT_MAX};
#pragma unroll
    for (int k=0;k<16;k++){
      const int j = idxr[k];
      const float gx = sx[j]-qx, gy = sy[j]-qy, gz = sz[j]-qz;
      float h[4];
#pragma unroll
      for (int oo=0;oo<4;oo++)
        h[oo] = btv[oo] + gx*wt[0][oo] + gy*wt[1][oo] + gz*wt[2][oo];
      const float4* fp = (const float4*)(sfs + j*12);
#pragma unroll
      for (int cc=0;cc<2;cc++){
        float4 f = fp[cc];
#pragma unroll
        for (int oo=0;oo<4;oo++)
          h[oo] += f.x*wt[3+4*cc][oo] + f.y*wt[4+4*cc][oo] + f.z*wt[5+4*cc][oo] + f.w*wt[6+4*cc][oo];
      }
#pragma unroll
      for (int oo=0;oo<4;oo++) acc[oo] = fmaxf(acc[oo], lrelu(h[oo]));
    }
    // reduce over the 16 m-values in this wave (lane bits 2..5), then one atomic.
#pragma unroll
    for (int oo=0;oo<4;oo++){
      float v = acc[oo];
      v += __shfl_xor(v, 4);
      v += __shfl_xor(v, 8);
      v += __shfl_xor(v, 16);
      v += __shfl_xor(v, 32);
      if ((threadIdx.x & 60) == 0)                 // one lane per (wave, og4)
        atomicAdd(&sred[o0+oo], v);
    }
  }
  __syncthreads();
  if (tid < 256){
    const int o = tid;
    float s = 0.f;
#pragma unroll 8
    for (int c=0;c<128;c++) s += sred[c]*We[c*256+o];
    out[b*256+o] = beF[o] + s*0.0078125f;          // mean over 128 queries
  }
}

extern "C" void kernel_launch(void* const* d_in, const int* in_sizes, int n_in,
                              void* d_out, int out_size, void* d_ws, size_t ws_size,
                              hipStream_t stream) {
  (void)in_sizes; (void)n_in; (void)out_size; (void)ws_size;
  const float* pc   = (const float*)d_in[0];
  const float* W0   = (const float*)d_in[1];
  const float* b0   = (const float*)d_in[2];
  const float* g0   = (const float*)d_in[3];
  const float* be0  = (const float*)d_in[4];
  const float* W1   = (const float*)d_in[5];
  const float* b1   = (const float*)d_in[6];
  const float* g1   = (const float*)d_in[7];
  const float* be1  = (const float*)d_in[8];
  const float* pcW  = (const float*)d_in[9];
  const float* pcb  = (const float*)d_in[10];
  const float* Ws   = (const float*)d_in[11];
  const float* bs   = (const float*)d_in[12];
  const float* Wc   = (const float*)d_in[13];
  const float* bc   = (const float*)d_in[14];
  const float* We   = (const float*)d_in[15];
  const float* beF  = (const float*)d_in[16];

  char* ws = (char*)d_ws;
  float4* cand0 = (float4*)ws;                        // 4 MB
  float*  feats = (float*)(ws + (4u<<20));            // 16 MB
  int*    idx1  = (int*)  (ws + (20u<<20));           // 8 MB
  float*  fsb   = (float*)(ws + (28u<<20));           // 4 MB
  int*    idx2  = (int*)  (ws + (32u<<20));           // 2 MB
  float*  out   = (float*)d_out;

  prep_kernel<<<1024, 256, 0, stream>>>(pc, W0,b0,g0,be0, W1,b1,g1,be1, cand0, feats);
  knn_kernel<2,1,512,2,1024><<<256, 1024, 0, stream>>>(cand0, idx1);
  knn_kernel<8,2,128,4, 512><<<256,  512, 0, stream>>>(cand0, idx2);
  feat1_kernel<<<256, 512, 0, stream>>>(cand0, feats, idx1, pcW, pcb, Ws, bs, fsb);
  feat2_kernel<<<256, 512, 0, stream>>>(cand0, fsb, idx2, Wc, bc, We, beF, out);
}